// Round 3
// baseline (1277.782 us; speedup 1.0000x reference)
//
#include <hip/hip_runtime.h>
#include <cstdint>
#include <cmath>

// ---------------------------------------------------------------------------
// Mamba3 block forward, MI355X (gfx950).
// B=2, S=4096 (8192 tokens), D_MODEL=1024, D_INNER=2048, NHEADS=32, HD=64,
// D_STATE=64, CHUNK=64, D_MLP=2560, PROJ=9248.
// Workspace budget: 250.5 MiB (see layout below). x2 lives in d_out.
// ---------------------------------------------------------------------------

typedef __bf16 bf16;
typedef __bf16 bf16x2 __attribute__((ext_vector_type(2)));
typedef __bf16 bf16x4 __attribute__((ext_vector_type(4)));
typedef __bf16 bf16x8 __attribute__((ext_vector_type(8)));
typedef float fx4 __attribute__((ext_vector_type(4)));

#define DEV __device__ __forceinline__

// ---- workspace layout (bytes) ---------------------------------------------
// proj (bf16 8192x8192): cols z[0,2048) xs->xg->ybf[2048,4096) B[4096,6144) C[6144,8192)
//   later: gu (8192x5120 bf16) at +0 ; m (8192x2560 bf16) at +83886080
#define OFF_PROJ    0ull
#define OFF_HHI     134217728ull   // 8192x1024 bf16 (h hi) ; later h2_bf
#define OFF_HLO     150994944ull   // 8192x1024 bf16 (h lo)
#define OFF_WTIN    167772160ull   // 8192x1024 bf16
#define OFF_WTHI    184549376ull   // 1152x1024 bf16
#define OFF_WTLO    186908672ull   // 1152x1024 bf16
#define OFF_PROJT   189267968ull   // 8192x1152 f32 (dt,theta) -- dead after scan_rope
#define OFF_BX      189267968ull   // 4096x4096 bf16 (written at ssd1, overlays projT)
#define OFF_STATES  222822400ull   // 4096x4096 bf16 -> FS in place; dead after ssd3
#define OFF_WTOUT   222822400ull   // 1024x2048 bf16 (written after ssd3, overlays states)
#define OFF_WTGU    227016704ull   // 5120x1024 bf16 (after ssd3)
#define OFF_WTD     237502464ull   // 1024x2560 bf16 (after ssd3)
#define OFF_ABUF    256376832ull   // 8192x32 f32 (per-token A)
#define OFF_XSUM    257425408ull   // 8192x32 f32
#define OFF_ROWSUM  258473984ull   // (2,64,32,64) f32
#define OFF_EXPA    260571136ull   // (2,64,32,64) f32
#define OFF_DCHUNK  262668288ull   // (2,64,32) f32
#define WS_NEEDED   262684672ull

#define OFF_GU      0ull
#define OFF_MBF     83886080ull

// ---------------------------------------------------------------------------
DEV void async_copy16(void* lds, const void* gptr) {
  __builtin_amdgcn_global_load_lds(
      (const __attribute__((address_space(1))) unsigned int*)(gptr),
      (__attribute__((address_space(3))) unsigned int*)(lds),
      16, 0, 0);
}

DEV float warp_sum64(float v) {
  #pragma unroll
  for (int o = 32; o; o >>= 1) v += __shfl_xor(v, o);
  return v;
}

DEV float softplus_f(float x) { return x > 20.f ? x : log1pf(expf(x)); }
DEV float sigmoid_f(float x) { return 1.f / (1.f + expf(-x)); }

// ---------------------------------------------------------------------------
// Transpose + cast fp32 (RxC slice, row stride ld, col offset col0) -> bf16 (Cp x R)
__global__ __launch_bounds__(256) void transpose_cast(
    const float* __restrict__ src, int ld, int col0,
    bf16* __restrict__ dst, int R, int C)
{
  __shared__ float tile[32][33];
  const int c0 = blockIdx.x * 32, r0 = blockIdx.y * 32;
  const int tx = threadIdx.x & 31, ty = threadIdx.x >> 5;
  #pragma unroll
  for (int ii = 0; ii < 4; ++ii) {
    int i = ty + ii * 8;
    int c = c0 + tx;
    tile[i][tx] = (c < C) ? src[(size_t)(r0 + i) * ld + col0 + c] : 0.f;
  }
  __syncthreads();
  #pragma unroll
  for (int ii = 0; ii < 4; ++ii) {
    int i = ty + ii * 8;
    dst[(size_t)(c0 + i) * R + r0 + tx] = (bf16)tile[tx][i];
  }
}

__global__ __launch_bounds__(256) void transpose_cast_hilo(
    const float* __restrict__ src, int ld, int col0,
    bf16* __restrict__ dhi, bf16* __restrict__ dlo, int R, int C)
{
  __shared__ float tile[32][33];
  const int c0 = blockIdx.x * 32, r0 = blockIdx.y * 32;
  const int tx = threadIdx.x & 31, ty = threadIdx.x >> 5;
  #pragma unroll
  for (int ii = 0; ii < 4; ++ii) {
    int i = ty + ii * 8;
    int c = c0 + tx;
    tile[i][tx] = (c < C) ? src[(size_t)(r0 + i) * ld + col0 + c] : 0.f;
  }
  __syncthreads();
  #pragma unroll
  for (int ii = 0; ii < 4; ++ii) {
    int i = ty + ii * 8;
    float v = tile[tx][i];
    bf16 hi = (bf16)v;
    size_t o = (size_t)(c0 + i) * R + r0 + tx;
    dhi[o] = hi;
    dlo[o] = (bf16)(v - (float)hi);
  }
}

// ---------------------------------------------------------------------------
__global__ __launch_bounds__(256) void rmsnorm_kernel(
    const float* __restrict__ x, const float* __restrict__ w,
    bf16* __restrict__ hi, bf16* __restrict__ lo)
{
  __shared__ float red[4];
  const size_t row = blockIdx.x;
  const int tid = threadIdx.x;
  float4 v = ((const float4*)(x + row * 1024))[tid];
  float ss = v.x * v.x + v.y * v.y + v.z * v.z + v.w * v.w;
  ss = warp_sum64(ss);
  if ((tid & 63) == 0) red[tid >> 6] = ss;
  __syncthreads();
  float tot = red[0] + red[1] + red[2] + red[3];
  float s = rsqrtf(tot * (1.f / 1024.f) + 1e-5f);
  float4 wv = ((const float4*)w)[tid];
  float h0 = v.x * s * wv.x, h1 = v.y * s * wv.y, h2 = v.z * s * wv.z, h3 = v.w * s * wv.w;
  bf16x4 hv = { (bf16)h0, (bf16)h1, (bf16)h2, (bf16)h3 };
  *(bf16x4*)(hi + row * 1024 + tid * 4) = hv;
  if (lo) {
    bf16x4 lv = { (bf16)(h0 - (float)hv[0]), (bf16)(h1 - (float)hv[1]),
                  (bf16)(h2 - (float)hv[2]), (bf16)(h3 - (float)hv[3]) };
    *(bf16x4*)(lo + row * 1024 + tid * 4) = lv;
  }
}

// ---------------------------------------------------------------------------
// bf16 GEMM, A(MxK) row stride lda, B(NxK) row-major (B^T of KxN), out MxN.
// 128x128 tile, BK=64, 4 waves, 16x16x32 MFMA, global_load_lds staging,
// XOR-swizzled LDS. MODE: 0=f32 store, 1=bf16 store, 2=f32 v+resid, 3=f32 +=
template <int MODE>
__global__ __launch_bounds__(256) void gemm_bt(
    const bf16* A, const bf16* B, void* Cout, const float* resid,
    int K, int lda, int ldc)
{
  __shared__ bf16 As[128 * 64];
  __shared__ bf16 Bs[128 * 64];
  const int tid = threadIdx.x, wid = tid >> 6, lane = tid & 63;
  const int m0 = blockIdx.y * 128, n0 = blockIdx.x * 128;
  const int wm = (wid & 1) * 64, wn = (wid >> 1) * 64;
  fx4 acc[4][4];
  #pragma unroll
  for (int i = 0; i < 4; ++i)
    #pragma unroll
    for (int j = 0; j < 4; ++j) { fx4 z = {0.f, 0.f, 0.f, 0.f}; acc[i][j] = z; }

  const int srow = wid * 32 + (lane >> 3);
  const int slot = lane & 7;

  for (int k0 = 0; k0 < K; k0 += 64) {
    __syncthreads();
    #pragma unroll
    for (int i = 0; i < 4; ++i) {
      int m = srow + i * 8;
      int cA = ((slot ^ (m & 7)) * 8);
      async_copy16(&As[wid * 2048 + i * 512], A + (size_t)(m0 + m) * lda + k0 + cA);
    }
    #pragma unroll
    for (int i = 0; i < 4; ++i) {
      int n = srow + i * 8;
      int cB = ((slot ^ (n & 7)) * 8);
      async_copy16(&Bs[wid * 2048 + i * 512], B + (size_t)(n0 + n) * K + k0 + cB);
    }
    __syncthreads();
    #pragma unroll
    for (int kk = 0; kk < 2; ++kk) {
      bf16x8 af[4], bfr[4];
      #pragma unroll
      for (int i = 0; i < 4; ++i) {
        int mm = wm + i * 16 + (lane & 15);
        int sA = (kk * 4 + (lane >> 4)) ^ (mm & 7);
        af[i] = *(const bf16x8*)&As[mm * 64 + sA * 8];
        int nn = wn + i * 16 + (lane & 15);
        int sB = (kk * 4 + (lane >> 4)) ^ (nn & 7);
        bfr[i] = *(const bf16x8*)&Bs[nn * 64 + sB * 8];
      }
      #pragma unroll
      for (int i = 0; i < 4; ++i)
        #pragma unroll
        for (int j = 0; j < 4; ++j)
          acc[i][j] = __builtin_amdgcn_mfma_f32_16x16x32_bf16(af[i], bfr[j], acc[i][j], 0, 0, 0);
    }
  }
  // C/D layout: col=lane&15, row=(lane>>4)*4+reg
  const int r0 = (lane >> 4) * 4, cc = lane & 15;
  #pragma unroll
  for (int i = 0; i < 4; ++i) {
    #pragma unroll
    for (int j = 0; j < 4; ++j) {
      #pragma unroll
      for (int r = 0; r < 4; ++r) {
        int m = m0 + wm + i * 16 + r0 + r;
        int n = n0 + wn + j * 16 + cc;
        size_t off = (size_t)m * ldc + n;
        float v = acc[i][j][r];
        if (MODE == 0) ((float*)Cout)[off] = v;
        else if (MODE == 1) ((bf16*)Cout)[off] = (bf16)v;
        else if (MODE == 2) ((float*)Cout)[off] = v + resid[off];
        else ((float*)Cout)[off] += v;
      }
    }
  }
}

// ---------------------------------------------------------------------------
// Per (token, head), IN PLACE on proj (stride 8192):
//   xg = xs*gamma at cols [2048,4096); B' = rms(B)+bias at [4096,6144);
//   C' = rms(C)+bias at [6144,8192); dt written back into projT col h.
__global__ __launch_bounds__(256) void prep_kernel(
    bf16* proj, float* projT,
    const float* __restrict__ A_log, const float* __restrict__ dt_bias,
    const float* __restrict__ B_bias, const float* __restrict__ C_bias,
    const float* __restrict__ Bn_w, const float* __restrict__ Cn_w,
    float* __restrict__ a_buf, float* __restrict__ xsum)
{
  const size_t bs = blockIdx.x;
  const int w = threadIdx.x >> 6, lane = threadIdx.x & 63;
  bf16* prow = proj + bs * 8192;
  float* trow = projT + bs * 1152;
  #pragma unroll 1
  for (int hh = 0; hh < 8; ++hh) {
    const int h = w * 8 + hh;
    float dtr = trow[h] + dt_bias[h];
    float dt = softplus_f(dtr);
    float a = -expf(A_log[h]) * dt;
    float alpha = expf(a);
    float gamma = (alpha - 1.f) / (a + 1e-6f) * 0.5f + 1.f;

    float xv = (float)prow[2048 + h * 64 + lane];
    float sx = warp_sum64(xv);
    prow[2048 + h * 64 + lane] = (bf16)(xv * gamma);
    if (lane == 0) { a_buf[bs * 32 + h] = a; xsum[bs * 32 + h] = sx; trow[h] = dt; }

    float bv = (float)prow[4096 + h * 64 + lane];
    float sb = warp_sum64(bv * bv);
    prow[4096 + h * 64 + lane] =
        (bf16)(bv * rsqrtf(sb * (1.f / 64.f) + 1e-5f) * Bn_w[lane] + B_bias[h * 64 + lane]);

    float cv = (float)prow[6144 + h * 64 + lane];
    float sc = warp_sum64(cv * cv);
    prow[6144 + h * 64 + lane] =
        (bf16)(cv * rsqrtf(sc * (1.f / 64.f) + 1e-5f) * Cn_w[lane] + C_bias[h * 64 + lane]);
  }
}

// ---------------------------------------------------------------------------
// Inclusive cumsum of dt*theta over time (per b,h,d) + RoPE B,C in place.
__global__ __launch_bounds__(256) void scan_rope_kernel(
    const float* __restrict__ projT, bf16* proj)
{
  const int g = blockIdx.x * 4 + (threadIdx.x >> 6);  // 0..2047
  const int lane = threadIdx.x & 63;
  const int b = g >> 10, rem = g & 1023, h = rem >> 5, d = rem & 31;
  float carry = 0.f;
  #pragma unroll 1
  for (int i = 0; i < 64; ++i) {
    size_t bs = (size_t)b * 4096 + i * 64 + lane;
    const float* tr = projT + bs * 1152;
    float v = tr[h] * tr[32 + h * 32 + d];   // dt * theta
    #pragma unroll
    for (int o = 1; o < 64; o <<= 1) { float u = __shfl_up(v, o); if (lane >= o) v += u; }
    v += carry;
    carry = __shfl(v, 63);
    float sn, cs;
    sincosf(v, &sn, &cs);
    size_t base = bs * 8192 + 4096 + h * 64 + 2 * d;  // B pair; C at +2048
    float b1 = (float)proj[base], b2 = (float)proj[base + 1];
    proj[base]     = (bf16)(cs * b1 - sn * b2);
    proj[base + 1] = (bf16)(sn * b1 + cs * b2);
    float c1 = (float)proj[base + 2048], c2 = (float)proj[base + 2049];
    proj[base + 2048] = (bf16)(cs * c1 - sn * c2);
    proj[base + 2049] = (bf16)(sn * c1 + cs * c2);
  }
}

// ---------------------------------------------------------------------------
// SSD stage 1, one block per (b,c,h).
__global__ __launch_bounds__(256) void ssd1_kernel(
    const bf16* __restrict__ proj, const float* __restrict__ a_buf,
    bf16* __restrict__ Bx, bf16* __restrict__ states,
    float* __restrict__ rowsum, float* __restrict__ expac, float* __restrict__ dchunk)
{
  __shared__ float xs[64][68];
  __shared__ float bsm[64][68];
  __shared__ float acum[64], dsv[64];
  const int blk = blockIdx.x;
  const int b = blk >> 11, c = (blk >> 5) & 63, h = blk & 31;
  const size_t bs0 = (size_t)b * 4096 + c * 64;
  const int tid = threadIdx.x;
  {
    int l = tid >> 2, p0 = (tid & 3) * 16;
    const bf16x8* xsrc = (const bf16x8*)(proj + (bs0 + l) * 8192 + 2048 + h * 64 + p0);
    bf16x8 u0 = xsrc[0], u1 = xsrc[1];
    const bf16x8* bsrc = (const bf16x8*)(proj + (bs0 + l) * 8192 + 4096 + h * 64 + p0);
    bf16x8 v0 = bsrc[0], v1 = bsrc[1];
    #pragma unroll
    for (int e = 0; e < 8; ++e) {
      xs[l][p0 + e] = (float)u0[e];  xs[l][p0 + 8 + e] = (float)u1[e];
      bsm[l][p0 + e] = (float)v0[e]; bsm[l][p0 + 8 + e] = (float)v1[e];
    }
  }
  if (tid < 64) {
    float v = a_buf[(bs0 + tid) * 32 + h];
    #pragma unroll
    for (int o = 1; o < 64; o <<= 1) { float u = __shfl_up(v, o); if (tid >= o) v += u; }
    acum[tid] = v;
    float a63 = __shfl(v, 63);
    dsv[tid] = expf(a63 - v);
    int gidx = ((b * 64 + c) * 32 + h) * 64 + tid;
    expac[gidx] = expf(v);
    if (tid == 63) dchunk[(b * 64 + c) * 32 + h] = expf(v);
  }
  __syncthreads();
  if (tid < 64) {
    float al = acum[tid];
    float rs = 0.f;
    for (int s = 0; s <= tid; ++s) rs += expf(al - acum[s]);
    rs += (float)(63 - tid);   // reference's unmasked upper-triangular exp(0)=1 terms
    rowsum[((b * 64 + c) * 32 + h) * 64 + tid] = rs;
  }
  const int p0 = (tid & 15) * 4, n0 = (tid >> 4) * 4;
  float aB[4][4] = {}, aS[4][4] = {};
  #pragma unroll 4
  for (int l = 0; l < 64; ++l) {
    float4 xv = *(const float4*)&xs[l][p0];
    float4 bv = *(const float4*)&bsm[l][n0];
    float dw = dsv[l];
    float xx[4] = { xv.x, xv.y, xv.z, xv.w };
    float bb[4] = { bv.x, bv.y, bv.z, bv.w };
    #pragma unroll
    for (int i = 0; i < 4; ++i) {
      float xd = xx[i] * dw;
      #pragma unroll
      for (int j = 0; j < 4; ++j) { aB[i][j] += xx[i] * bb[j]; aS[i][j] += xd * bb[j]; }
    }
  }
  const size_t obase = ((size_t)(b * 64 + c) * 32 + h) * 4096;
  #pragma unroll
  for (int i = 0; i < 4; ++i) {
    bf16x4 vb = { (bf16)aB[i][0], (bf16)aB[i][1], (bf16)aB[i][2], (bf16)aB[i][3] };
    bf16x4 vs = { (bf16)aS[i][0], (bf16)aS[i][1], (bf16)aS[i][2], (bf16)aS[i][3] };
    *(bf16x4*)(Bx + obase + (p0 + i) * 64 + n0) = vb;
    *(bf16x4*)(states + obase + (p0 + i) * 64 + n0) = vs;
  }
}

// ---------------------------------------------------------------------------
// SSD stage 2: inclusive scan over chunks (f32 carry, bf16 storage).
__global__ __launch_bounds__(256) void ssd2_kernel(
    bf16* __restrict__ states, const float* __restrict__ dchunk)
{
  const int blk = blockIdx.x;  // 256 = b(2) x h(32) x q(4)
  const int b = blk >> 7, h = (blk >> 2) & 31, q = blk & 3;
  const int e0 = q * 1024 + threadIdx.x * 4;
  float fs0 = 0.f, fs1 = 0.f, fs2 = 0.f, fs3 = 0.f;
  #pragma unroll 1
  for (int c = 0; c < 64; ++c) {
    size_t idx = (((size_t)(b * 64 + c) * 32 + h) * 4096) + e0;
    float dec = dchunk[(b * 64 + c) * 32 + h];
    bf16x4 st = *(const bf16x4*)(states + idx);
    fs0 = fs0 * dec + (float)st[0]; fs1 = fs1 * dec + (float)st[1];
    fs2 = fs2 * dec + (float)st[2]; fs3 = fs3 * dec + (float)st[3];
    bf16x4 o = { (bf16)fs0, (bf16)fs1, (bf16)fs2, (bf16)fs3 };
    *(bf16x4*)(states + idx) = o;
  }
}

// ---------------------------------------------------------------------------
// SSD stage 3, one block per (b,c,h):
//   Y[l,p] = rowsum[l]*(C·Bx^T)[l,p] + expac[l]*(C·FS^T)[l,p] + D[h]*xsum[l]
//   proj cols [2048,4096) <- (bf16)(Y * silu(z))   (z from cols [0,2048))
__global__ __launch_bounds__(256) void ssd3_kernel(
    bf16* proj, const bf16* __restrict__ Bx, const bf16* __restrict__ FS,
    const float* __restrict__ rowsum, const float* __restrict__ expac,
    const float* __restrict__ xsum, const float* __restrict__ D_param)
{
  __shared__ float Cs[64][68], Bxs[64][68], FSs[64][68];
  __shared__ float rs_s[64], ea_s[64];
  const int blk = blockIdx.x;
  const int b = blk >> 11, c = (blk >> 5) & 63, h = blk & 31;
  const size_t bs0 = (size_t)b * 4096 + c * 64;
  const int tid = threadIdx.x;
  {
    int l = tid >> 2, q0 = (tid & 3) * 16;
    const bf16x8* csrc = (const bf16x8*)(proj + (bs0 + l) * 8192 + 6144 + h * 64 + q0);
    bf16x8 u0 = csrc[0], u1 = csrc[1];
    size_t mb = ((size_t)(b * 64 + c) * 32 + h) * 4096 + l * 64 + q0;
    const bf16x8* bx8 = (const bf16x8*)(Bx + mb);
    bf16x8 b0 = bx8[0], b1 = bx8[1];
    const bf16x8* fs8 = (const bf16x8*)(FS + mb);
    bf16x8 f0 = fs8[0], f1 = fs8[1];
    #pragma unroll
    for (int e = 0; e < 8; ++e) {
      Cs[l][q0 + e] = (float)u0[e];  Cs[l][q0 + 8 + e] = (float)u1[e];
      Bxs[l][q0 + e] = (float)b0[e]; Bxs[l][q0 + 8 + e] = (float)b1[e];
      FSs[l][q0 + e] = (float)f0[e]; FSs[l][q0 + 8 + e] = (float)f1[e];
    }
  }
  if (tid < 64) {
    int gidx = ((b * 64 + c) * 32 + h) * 64 + tid;
    rs_s[tid] = rowsum[gidx];
    ea_s[tid] = expac[gidx];
  }
  __syncthreads();
  const int l0 = (tid & 15) * 4, p0 = (tid >> 4) * 4;
  float a1[4][4] = {}, a2[4][4] = {};
  #pragma unroll 2
  for (int n = 0; n < 64; n += 4) {
    float4 cv[4], bx[4], fv[4];
    #pragma unroll
    for (int i = 0; i < 4; ++i) cv[i] = *(const float4*)&Cs[l0 + i][n];
    #pragma unroll
    for (int j = 0; j < 4; ++j) { bx[j] = *(const float4*)&Bxs[p0 + j][n]; fv[j] = *(const float4*)&FSs[p0 + j][n]; }
    #pragma unroll
    for (int i = 0; i < 4; ++i)
      #pragma unroll
      for (int j = 0; j < 4; ++j) {
        a1[i][j] += cv[i].x * bx[j].x + cv[i].y * bx[j].y + cv[i].z * bx[j].z + cv[i].w * bx[j].w;
        a2[i][j] += cv[i].x * fv[j].x + cv[i].y * fv[j].y + cv[i].z * fv[j].z + cv[i].w * fv[j].w;
      }
  }
  const float dpar = D_param[h];
  #pragma unroll
  for (int i = 0; i < 4; ++i) {
    int l = l0 + i;
    size_t bs = bs0 + l;
    float sk = dpar * xsum[bs * 32 + h];
    float r = rs_s[l], e = ea_s[l];
    #pragma unroll
    for (int j = 0; j < 4; ++j) {
      int p = p0 + j;
      float y = r * a1[i][j] + e * a2[i][j] + sk;
      float z = (float)proj[bs * 8192 + h * 64 + p];
      proj[bs * 8192 + 2048 + h * 64 + p] = (bf16)(y * z * sigmoid_f(z));
    }
  }
}

// ---------------------------------------------------------------------------
__global__ __launch_bounds__(256) void silu_mul_kernel(
    const bf16* __restrict__ gu, bf16* __restrict__ m)
{
  const size_t row = blockIdx.y;
  const int col2 = blockIdx.x * 256 + threadIdx.x;  // 0..1279
  const size_t gi = row * 5120 + col2 * 2;
  bf16x2 g = *(const bf16x2*)(gu + gi);
  bf16x2 u = *(const bf16x2*)(gu + gi + 2560);
  float g0 = (float)g[0], g1 = (float)g[1];
  float m0 = g0 * sigmoid_f(g0) * (float)u[0];
  float m1 = g1 * sigmoid_f(g1) * (float)u[1];
  bf16x2 mv = { (bf16)m0, (bf16)m1 };
  *(bf16x2*)(m + row * 2560 + col2 * 2) = mv;
}

// ---------------------------------------------------------------------------
extern "C" void kernel_launch(void* const* d_in, const int* in_sizes, int n_in,
                              void* d_out, int out_size, void* d_ws, size_t ws_size,
                              hipStream_t stream) {
  (void)in_sizes; (void)n_in; (void)out_size;
  if (ws_size < WS_NEEDED) return;  // diagnostic guard: fail absmax, not SIGABRT
  const float* x       = (const float*)d_in[0];
  const float* n1w     = (const float*)d_in[1];
  const float* n2w     = (const float*)d_in[2];
  const float* W_in    = (const float*)d_in[3];
  const float* W_out   = (const float*)d_in[4];
  const float* A_log   = (const float*)d_in[5];
  const float* D_param = (const float*)d_in[6];
  const float* dt_bias = (const float*)d_in[7];
  const float* B_bias  = (const float*)d_in[8];
  const float* C_bias  = (const float*)d_in[9];
  const float* Bn_w    = (const float*)d_in[10];
  const float* Cn_w    = (const float*)d_in[11];
  const float* Wg      = (const float*)d_in[12];
  const float* Wu      = (const float*)d_in[13];
  const float* Wd      = (const float*)d_in[14];
  float* out = (float*)d_out;
  char* ws = (char*)d_ws;

  bf16*  proj   = (bf16*)(ws + OFF_PROJ);
  float* projT  = (float*)(ws + OFF_PROJT);
  bf16*  h_hi   = (bf16*)(ws + OFF_HHI);
  bf16*  h_lo   = (bf16*)(ws + OFF_HLO);
  bf16*  Wt_in  = (bf16*)(ws + OFF_WTIN);
  bf16*  Wt_hi  = (bf16*)(ws + OFF_WTHI);
  bf16*  Wt_lo  = (bf16*)(ws + OFF_WTLO);
  bf16*  Wt_out = (bf16*)(ws + OFF_WTOUT);
  bf16*  Wt_gu  = (bf16*)(ws + OFF_WTGU);
  bf16*  Wt_d   = (bf16*)(ws + OFF_WTD);
  bf16*  Bx     = (bf16*)(ws + OFF_BX);
  bf16*  states = (bf16*)(ws + OFF_STATES);
  float* a_buf  = (float*)(ws + OFF_ABUF);
  float* xsum_  = (float*)(ws + OFF_XSUM);
  float* rowsum = (float*)(ws + OFF_ROWSUM);
  float* expac  = (float*)(ws + OFF_EXPA);
  float* dchunk = (float*)(ws + OFF_DCHUNK);
  bf16*  ybf    = proj + 2048;               // cols [2048,4096) of proj, lda 8192
  bf16*  gubf   = (bf16*)(ws + OFF_GU);
  bf16*  mbf    = (bf16*)(ws + OFF_MBF);
  bf16*  h2bf   = h_hi;                      // reuse after proj GEMMs
  float* x2     = out;                       // x2 lives in d_out

  // --- weight transposes needed up-front ---
  transpose_cast<<<dim3(256, 32), 256, 0, stream>>>(W_in, 9248, 0, Wt_in, 1024, 8192);
  transpose_cast_hilo<<<dim3(36, 32), 256, 0, stream>>>(W_in, 9248, 8192, Wt_hi, Wt_lo, 1024, 1056);

  // --- norm1 (hi/lo split for the precision-critical dt/theta tail GEMM) ---
  rmsnorm_kernel<<<8192, 256, 0, stream>>>(x, n1w, h_hi, h_lo);

  // --- in-projection ---
  gemm_bt<1><<<dim3(64, 64), 256, 0, stream>>>(h_hi, Wt_in, proj, nullptr, 1024, 1024, 8192);
  gemm_bt<0><<<dim3(9, 64), 256, 0, stream>>>(h_hi, Wt_hi, projT, nullptr, 1024, 1024, 1152);
  gemm_bt<3><<<dim3(9, 64), 256, 0, stream>>>(h_hi, Wt_lo, projT, nullptr, 1024, 1024, 1152);
  gemm_bt<3><<<dim3(9, 64), 256, 0, stream>>>(h_lo, Wt_hi, projT, nullptr, 1024, 1024, 1152);

  // --- per-token/head prep (in place) + RoPE scan ---
  prep_kernel<<<8192, 256, 0, stream>>>(proj, projT, A_log, dt_bias, B_bias, C_bias,
                                        Bn_w, Cn_w, a_buf, xsum_);
  scan_rope_kernel<<<512, 256, 0, stream>>>(projT, proj);

  // --- SSD ---
  ssd1_kernel<<<4096, 256, 0, stream>>>(proj, a_buf, Bx, states, rowsum, expac, dchunk);
  ssd2_kernel<<<256, 256, 0, stream>>>(states, dchunk);
  ssd3_kernel<<<4096, 256, 0, stream>>>(proj, Bx, states, rowsum, expac, xsum_, D_param);

  // --- late weight transposes (overlay dead states region) ---
  transpose_cast<<<dim3(32, 64), 256, 0, stream>>>(W_out, 1024, 0, Wt_out, 2048, 1024);
  transpose_cast<<<dim3(80, 32), 256, 0, stream>>>(Wg, 2560, 0, Wt_gu, 1024, 2560);
  transpose_cast<<<dim3(80, 32), 256, 0, stream>>>(Wu, 2560, 0, Wt_gu + (size_t)2560 * 1024, 1024, 2560);
  transpose_cast<<<dim3(32, 80), 256, 0, stream>>>(Wd, 1024, 0, Wt_d, 2560, 1024);

  // --- out-projection + residual (x2 -> d_out) ---
  gemm_bt<2><<<dim3(8, 64), 256, 0, stream>>>(ybf, Wt_out, x2, x, 2048, 8192, 1024);

  // --- MLP ---
  rmsnorm_kernel<<<8192, 256, 0, stream>>>(x2, n2w, h2bf, nullptr);
  gemm_bt<1><<<dim3(40, 64), 256, 0, stream>>>(h2bf, Wt_gu, gubf, nullptr, 1024, 1024, 5120);
  silu_mul_kernel<<<dim3(5, 8192), 256, 0, stream>>>(gubf, mbf);
  gemm_bt<2><<<dim3(8, 64), 256, 0, stream>>>(mbf, Wt_d, out, x2, 2560, 2560, 1024);
}

// Round 4
// 1061.435 us; speedup vs baseline: 1.2038x; 1.2038x over previous
//
#include <hip/hip_runtime.h>
#include <cstdint>
#include <cmath>

// ---------------------------------------------------------------------------
// Mamba3 block forward, MI355X (gfx950).
// B=2, S=4096 (8192 tokens), D_MODEL=1024, D_INNER=2048, NHEADS=32, HD=64,
// D_STATE=64, CHUNK=64, D_MLP=2560, PROJ=9248.
// Workspace budget: 250.5 MiB. x2 lives in d_out.
// ---------------------------------------------------------------------------

typedef __bf16 bf16;
typedef __bf16 bf16x2 __attribute__((ext_vector_type(2)));
typedef __bf16 bf16x4 __attribute__((ext_vector_type(4)));
typedef __bf16 bf16x8 __attribute__((ext_vector_type(8)));
typedef float fx4 __attribute__((ext_vector_type(4)));

#define DEV __device__ __forceinline__

// ---- workspace layout (bytes) ---------------------------------------------
// proj (bf16 8192x8192): cols z[0,2048) xs->xg->ybf[2048,4096) B[4096,6144) C[6144,8192)
//   later: gu (8192x5120 bf16) at +0 ; m (8192x2560 bf16) at +83886080
#define OFF_PROJ    0ull
#define OFF_HHI     134217728ull   // 8192x1024 bf16 (h hi) ; later h2_bf
#define OFF_HLO     150994944ull   // 8192x1024 bf16 (h lo) ; later S (chunk sums, 512KB)
#define OFF_WTIN    167772160ull   // 8192x1024 bf16
#define OFF_WTHI    184549376ull   // 1152x1024 bf16
#define OFF_WTLO    186908672ull   // 1152x1024 bf16
#define OFF_PROJT   189267968ull   // 8192x1152 f32 (dt,theta) -- dead after rope
#define OFF_BX      189267968ull   // 4096x4096 bf16 (written at ssd1, overlays projT)
#define OFF_STATES  222822400ull   // 4096x4096 bf16 -> FS in place; dead after ssd3
#define OFF_WTOUT   222822400ull   // 1024x2048 bf16 (after ssd3, overlays states)
#define OFF_WTGU    227016704ull   // 5120x1024 bf16 (after ssd3)
#define OFF_WTD     237502464ull   // 1024x2560 bf16 (after ssd3)
#define OFF_ABUF    256376832ull   // 8192x32 f32 (per-token A)
#define OFF_XSUM    257425408ull   // 8192x32 f32
#define OFF_ROWSUM  258473984ull   // (2,64,32,64) f32
#define OFF_EXPA    260571136ull   // (2,64,32,64) f32
#define OFF_DCHUNK  262668288ull   // (2,64,32) f32
#define WS_NEEDED   262684672ull

#define OFF_GU      0ull
#define OFF_MBF     83886080ull

// ---------------------------------------------------------------------------
DEV void async_copy16(void* lds, const void* gptr) {
  __builtin_amdgcn_global_load_lds(
      (const __attribute__((address_space(1))) unsigned int*)(gptr),
      (__attribute__((address_space(3))) unsigned int*)(lds),
      16, 0, 0);
}

DEV float warp_sum64(float v) {
  #pragma unroll
  for (int o = 32; o; o >>= 1) v += __shfl_xor(v, o);
  return v;
}

DEV float softplus_f(float x) { return x > 20.f ? x : log1pf(expf(x)); }
DEV float sigmoid_f(float x) { return 1.f / (1.f + expf(-x)); }

// ---------------------------------------------------------------------------
// Transpose + cast fp32 (RxC slice, row stride ld, col offset col0) -> bf16 (Cp x R)
__global__ __launch_bounds__(256) void transpose_cast(
    const float* __restrict__ src, int ld, int col0,
    bf16* __restrict__ dst, int R, int C)
{
  __shared__ float tile[32][33];
  const int c0 = blockIdx.x * 32, r0 = blockIdx.y * 32;
  const int tx = threadIdx.x & 31, ty = threadIdx.x >> 5;
  #pragma unroll
  for (int ii = 0; ii < 4; ++ii) {
    int i = ty + ii * 8;
    int c = c0 + tx;
    tile[i][tx] = (c < C) ? src[(size_t)(r0 + i) * ld + col0 + c] : 0.f;
  }
  __syncthreads();
  #pragma unroll
  for (int ii = 0; ii < 4; ++ii) {
    int i = ty + ii * 8;
    dst[(size_t)(c0 + i) * R + r0 + tx] = (bf16)tile[tx][i];
  }
}

__global__ __launch_bounds__(256) void transpose_cast_hilo(
    const float* __restrict__ src, int ld, int col0,
    bf16* __restrict__ dhi, bf16* __restrict__ dlo, int R, int C)
{
  __shared__ float tile[32][33];
  const int c0 = blockIdx.x * 32, r0 = blockIdx.y * 32;
  const int tx = threadIdx.x & 31, ty = threadIdx.x >> 5;
  #pragma unroll
  for (int ii = 0; ii < 4; ++ii) {
    int i = ty + ii * 8;
    int c = c0 + tx;
    tile[i][tx] = (c < C) ? src[(size_t)(r0 + i) * ld + col0 + c] : 0.f;
  }
  __syncthreads();
  #pragma unroll
  for (int ii = 0; ii < 4; ++ii) {
    int i = ty + ii * 8;
    float v = tile[tx][i];
    bf16 hi = (bf16)v;
    size_t o = (size_t)(c0 + i) * R + r0 + tx;
    dhi[o] = hi;
    dlo[o] = (bf16)(v - (float)hi);
  }
}

// ---------------------------------------------------------------------------
__global__ __launch_bounds__(256) void rmsnorm_kernel(
    const float* __restrict__ x, const float* __restrict__ w,
    bf16* __restrict__ hi, bf16* __restrict__ lo)
{
  __shared__ float red[4];
  const size_t row = blockIdx.x;
  const int tid = threadIdx.x;
  float4 v = ((const float4*)(x + row * 1024))[tid];
  float ss = v.x * v.x + v.y * v.y + v.z * v.z + v.w * v.w;
  ss = warp_sum64(ss);
  if ((tid & 63) == 0) red[tid >> 6] = ss;
  __syncthreads();
  float tot = red[0] + red[1] + red[2] + red[3];
  float s = rsqrtf(tot * (1.f / 1024.f) + 1e-5f);
  float4 wv = ((const float4*)w)[tid];
  float h0 = v.x * s * wv.x, h1 = v.y * s * wv.y, h2 = v.z * s * wv.z, h3 = v.w * s * wv.w;
  bf16x4 hv = { (bf16)h0, (bf16)h1, (bf16)h2, (bf16)h3 };
  *(bf16x4*)(hi + row * 1024 + tid * 4) = hv;
  if (lo) {
    bf16x4 lv = { (bf16)(h0 - (float)hv[0]), (bf16)(h1 - (float)hv[1]),
                  (bf16)(h2 - (float)hv[2]), (bf16)(h3 - (float)hv[3]) };
    *(bf16x4*)(lo + row * 1024 + tid * 4) = lv;
  }
}

// ---------------------------------------------------------------------------
// bf16 GEMM, A(MxK) row stride lda, B(NxK) row-major (B^T of KxN), out MxN.
// 128x128 tile, BK=64, 4 waves, 16x16x32 MFMA, global_load_lds staging,
// XOR-swizzled LDS. MODE: 0=f32 store, 1=bf16 store, 2=f32 v+resid, 3=f32 +=
template <int MODE>
__global__ __launch_bounds__(256) void gemm_bt(
    const bf16* A, const bf16* B, void* Cout, const float* resid,
    int K, int lda, int ldc)
{
  __shared__ bf16 As[128 * 64];
  __shared__ bf16 Bs[128 * 64];
  const int tid = threadIdx.x, wid = tid >> 6, lane = tid & 63;
  const int m0 = blockIdx.y * 128, n0 = blockIdx.x * 128;
  const int wm = (wid & 1) * 64, wn = (wid >> 1) * 64;
  fx4 acc[4][4];
  #pragma unroll
  for (int i = 0; i < 4; ++i)
    #pragma unroll
    for (int j = 0; j < 4; ++j) { fx4 z = {0.f, 0.f, 0.f, 0.f}; acc[i][j] = z; }

  const int srow = wid * 32 + (lane >> 3);
  const int slot = lane & 7;

  for (int k0 = 0; k0 < K; k0 += 64) {
    __syncthreads();
    #pragma unroll
    for (int i = 0; i < 4; ++i) {
      int m = srow + i * 8;
      int cA = ((slot ^ (m & 7)) * 8);
      async_copy16(&As[wid * 2048 + i * 512], A + (size_t)(m0 + m) * lda + k0 + cA);
    }
    #pragma unroll
    for (int i = 0; i < 4; ++i) {
      int n = srow + i * 8;
      int cB = ((slot ^ (n & 7)) * 8);
      async_copy16(&Bs[wid * 2048 + i * 512], B + (size_t)(n0 + n) * K + k0 + cB);
    }
    __syncthreads();
    #pragma unroll
    for (int kk = 0; kk < 2; ++kk) {
      bf16x8 af[4], bfr[4];
      #pragma unroll
      for (int i = 0; i < 4; ++i) {
        int mm = wm + i * 16 + (lane & 15);
        int sA = (kk * 4 + (lane >> 4)) ^ (mm & 7);
        af[i] = *(const bf16x8*)&As[mm * 64 + sA * 8];
        int nn = wn + i * 16 + (lane & 15);
        int sB = (kk * 4 + (lane >> 4)) ^ (nn & 7);
        bfr[i] = *(const bf16x8*)&Bs[nn * 64 + sB * 8];
      }
      #pragma unroll
      for (int i = 0; i < 4; ++i)
        #pragma unroll
        for (int j = 0; j < 4; ++j)
          acc[i][j] = __builtin_amdgcn_mfma_f32_16x16x32_bf16(af[i], bfr[j], acc[i][j], 0, 0, 0);
    }
  }
  // C/D layout: col=lane&15, row=(lane>>4)*4+reg
  const int r0 = (lane >> 4) * 4, cc = lane & 15;
  #pragma unroll
  for (int i = 0; i < 4; ++i) {
    #pragma unroll
    for (int j = 0; j < 4; ++j) {
      #pragma unroll
      for (int r = 0; r < 4; ++r) {
        int m = m0 + wm + i * 16 + r0 + r;
        int n = n0 + wn + j * 16 + cc;
        size_t off = (size_t)m * ldc + n;
        float v = acc[i][j][r];
        if (MODE == 0) ((float*)Cout)[off] = v;
        else if (MODE == 1) ((bf16*)Cout)[off] = (bf16)v;
        else if (MODE == 2) ((float*)Cout)[off] = v + resid[off];
        else ((float*)Cout)[off] += v;
      }
    }
  }
}

// ---------------------------------------------------------------------------
// Per (token, head), IN PLACE on proj (stride 8192):
//   xg = xs*gamma at cols [2048,4096); B' = rms(B)+bias at [4096,6144);
//   C' = rms(C)+bias at [6144,8192); dt written back into projT col h.
__global__ __launch_bounds__(256) void prep_kernel(
    bf16* proj, float* projT,
    const float* __restrict__ A_log, const float* __restrict__ dt_bias,
    const float* __restrict__ B_bias, const float* __restrict__ C_bias,
    const float* __restrict__ Bn_w, const float* __restrict__ Cn_w,
    float* __restrict__ a_buf, float* __restrict__ xsum)
{
  const size_t bs = blockIdx.x;
  const int w = threadIdx.x >> 6, lane = threadIdx.x & 63;
  bf16* prow = proj + bs * 8192;
  float* trow = projT + bs * 1152;
  #pragma unroll 1
  for (int hh = 0; hh < 8; ++hh) {
    const int h = w * 8 + hh;
    float dtr = trow[h] + dt_bias[h];
    float dt = softplus_f(dtr);
    float a = -expf(A_log[h]) * dt;
    float alpha = expf(a);
    float gamma = (alpha - 1.f) / (a + 1e-6f) * 0.5f + 1.f;

    float xv = (float)prow[2048 + h * 64 + lane];
    float sx = warp_sum64(xv);
    prow[2048 + h * 64 + lane] = (bf16)(xv * gamma);
    if (lane == 0) { a_buf[bs * 32 + h] = a; xsum[bs * 32 + h] = sx; trow[h] = dt; }

    float bv = (float)prow[4096 + h * 64 + lane];
    float sb = warp_sum64(bv * bv);
    prow[4096 + h * 64 + lane] =
        (bf16)(bv * rsqrtf(sb * (1.f / 64.f) + 1e-5f) * Bn_w[lane] + B_bias[h * 64 + lane]);

    float cv = (float)prow[6144 + h * 64 + lane];
    float sc = warp_sum64(cv * cv);
    prow[6144 + h * 64 + lane] =
        (bf16)(cv * rsqrtf(sc * (1.f / 64.f) + 1e-5f) * Cn_w[lane] + C_bias[h * 64 + lane]);
  }
}

// ---------------------------------------------------------------------------
// Chunk sums of dt*theta: S[(b*64+c)][h*32+d] = sum_{t in chunk} dt[t][h]*theta[t][h][d]
// One block per (b,c); LDS-stage 8 token-rows of projT (cols [0,1056)) at a time.
__global__ __launch_bounds__(256) void chunk_sum_kernel(
    const float* __restrict__ projT, float* __restrict__ S)
{
  __shared__ float lds[8448];   // 8 rows x 1056 cols
  const int blk = blockIdx.x;                 // b*64 + c
  const size_t row0 = (size_t)blk * 64;       // (b*64+c)*64 = b*4096 + c*64
  const int tid = threadIdx.x;
  float s[4] = {0.f, 0.f, 0.f, 0.f};
  #pragma unroll 1
  for (int batch = 0; batch < 8; ++batch) {
    __syncthreads();
    const float* src = projT + (row0 + batch * 8) * 1152;
    #pragma unroll
    for (int i = 0; i < 33; ++i) {
      int idx = i * 256 + tid;               // 0..8447, idx = r*1056+col
      int r = idx / 1056, col = idx - r * 1056;
      lds[idx] = src[r * 1152 + col];
    }
    __syncthreads();
    #pragma unroll
    for (int k = 0; k < 4; ++k) {
      int hd = tid + 256 * k;
      int h = hd >> 5, d = hd & 31;
      #pragma unroll
      for (int r = 0; r < 8; ++r)
        s[k] += lds[r * 1056 + h] * lds[r * 1056 + 32 + h * 32 + d];
    }
  }
  #pragma unroll
  for (int k = 0; k < 4; ++k)
    S[(size_t)blk * 1024 + tid + 256 * k] = s[k];
}

// ---------------------------------------------------------------------------
// RoPE apply, one block per (b,c,h). Phase 1: per wave, 8 d values; chunk
// offset from S + intra-chunk shfl scan; sincos -> LDS [token][d].
// Phase 2: vectorized in-place rotation of B,C rows (coalesced 16B).
__global__ __launch_bounds__(256) void rope_kernel(
    bf16* proj, const float* __restrict__ projT, const float* __restrict__ S)
{
  __shared__ float angs[64 * 33], angc[64 * 33];
  const int blk = blockIdx.x;
  const int b = blk >> 11, c = (blk >> 5) & 63, h = blk & 31;
  const size_t t0 = (size_t)b * 4096 + c * 64;
  const int w = threadIdx.x >> 6, lane = threadIdx.x & 63;
  const float* tr = projT + (t0 + lane) * 1152;
  float dtv = tr[h];
  #pragma unroll 1
  for (int j = 0; j < 8; ++j) {
    int d = w * 8 + j;
    float sv = (lane < c) ? S[(size_t)(b * 64 + lane) * 1024 + h * 32 + d] : 0.f;
    float off = warp_sum64(sv);
    float v = dtv * tr[32 + h * 32 + d];
    #pragma unroll
    for (int o = 1; o < 64; o <<= 1) { float u = __shfl_up(v, o); if (lane >= o) v += u; }
    float ang = off + v;
    float sn, cs;
    sincosf(ang, &sn, &cs);
    angs[lane * 33 + d] = sn;
    angc[lane * 33 + d] = cs;
  }
  __syncthreads();
  const int tt = threadIdx.x >> 2, q = threadIdx.x & 3;   // token tt, quarter q
  const size_t base = (t0 + tt) * 8192 + 4096 + h * 64 + q * 16;
  #pragma unroll
  for (int m = 0; m < 2; ++m) {   // m=0: B, m=1: C
    bf16* p = proj + base + m * 2048;
    bf16x8 v0 = *(const bf16x8*)(p);
    bf16x8 v1 = *(const bf16x8*)(p + 8);
    bf16x8 r0, r1;
    #pragma unroll
    for (int pp = 0; pp < 4; ++pp) {
      int d = q * 8 + pp;
      float e1 = (float)v0[2 * pp], e2 = (float)v0[2 * pp + 1];
      float sn = angs[tt * 33 + d], cs = angc[tt * 33 + d];
      r0[2 * pp]     = (bf16)(cs * e1 - sn * e2);
      r0[2 * pp + 1] = (bf16)(sn * e1 + cs * e2);
    }
    #pragma unroll
    for (int pp = 0; pp < 4; ++pp) {
      int d = q * 8 + 4 + pp;
      float e1 = (float)v1[2 * pp], e2 = (float)v1[2 * pp + 1];
      float sn = angs[tt * 33 + d], cs = angc[tt * 33 + d];
      r1[2 * pp]     = (bf16)(cs * e1 - sn * e2);
      r1[2 * pp + 1] = (bf16)(sn * e1 + cs * e2);
    }
    *(bf16x8*)(p) = r0;
    *(bf16x8*)(p + 8) = r1;
  }
}

// ---------------------------------------------------------------------------
// SSD stage 1, one block per (b,c,h).
__global__ __launch_bounds__(256) void ssd1_kernel(
    const bf16* __restrict__ proj, const float* __restrict__ a_buf,
    bf16* __restrict__ Bx, bf16* __restrict__ states,
    float* __restrict__ rowsum, float* __restrict__ expac, float* __restrict__ dchunk)
{
  __shared__ float xs[64][68];
  __shared__ float bsm[64][68];
  __shared__ float acum[64], dsv[64];
  const int blk = blockIdx.x;
  const int b = blk >> 11, c = (blk >> 5) & 63, h = blk & 31;
  const size_t bs0 = (size_t)b * 4096 + c * 64;
  const int tid = threadIdx.x;
  {
    int l = tid >> 2, p0 = (tid & 3) * 16;
    const bf16x8* xsrc = (const bf16x8*)(proj + (bs0 + l) * 8192 + 2048 + h * 64 + p0);
    bf16x8 u0 = xsrc[0], u1 = xsrc[1];
    const bf16x8* bsrc = (const bf16x8*)(proj + (bs0 + l) * 8192 + 4096 + h * 64 + p0);
    bf16x8 v0 = bsrc[0], v1 = bsrc[1];
    #pragma unroll
    for (int e = 0; e < 8; ++e) {
      xs[l][p0 + e] = (float)u0[e];  xs[l][p0 + 8 + e] = (float)u1[e];
      bsm[l][p0 + e] = (float)v0[e]; bsm[l][p0 + 8 + e] = (float)v1[e];
    }
  }
  if (tid < 64) {
    float v = a_buf[(bs0 + tid) * 32 + h];
    #pragma unroll
    for (int o = 1; o < 64; o <<= 1) { float u = __shfl_up(v, o); if (tid >= o) v += u; }
    acum[tid] = v;
    float a63 = __shfl(v, 63);
    dsv[tid] = expf(a63 - v);
    int gidx = ((b * 64 + c) * 32 + h) * 64 + tid;
    expac[gidx] = expf(v);
    if (tid == 63) dchunk[(b * 64 + c) * 32 + h] = expf(v);
  }
  __syncthreads();
  if (tid < 64) {
    float al = acum[tid];
    float rs = 0.f;
    for (int s = 0; s <= tid; ++s) rs += expf(al - acum[s]);
    rs += (float)(63 - tid);   // reference's unmasked upper-triangular exp(0)=1 terms
    rowsum[((b * 64 + c) * 32 + h) * 64 + tid] = rs;
  }
  const int p0 = (tid & 15) * 4, n0 = (tid >> 4) * 4;
  float aB[4][4] = {}, aS[4][4] = {};
  #pragma unroll 4
  for (int l = 0; l < 64; ++l) {
    float4 xv = *(const float4*)&xs[l][p0];
    float4 bv = *(const float4*)&bsm[l][n0];
    float dw = dsv[l];
    float xx[4] = { xv.x, xv.y, xv.z, xv.w };
    float bb[4] = { bv.x, bv.y, bv.z, bv.w };
    #pragma unroll
    for (int i = 0; i < 4; ++i) {
      float xd = xx[i] * dw;
      #pragma unroll
      for (int j = 0; j < 4; ++j) { aB[i][j] += xx[i] * bb[j]; aS[i][j] += xd * bb[j]; }
    }
  }
  const size_t obase = ((size_t)(b * 64 + c) * 32 + h) * 4096;
  #pragma unroll
  for (int i = 0; i < 4; ++i) {
    bf16x4 vb = { (bf16)aB[i][0], (bf16)aB[i][1], (bf16)aB[i][2], (bf16)aB[i][3] };
    bf16x4 vs = { (bf16)aS[i][0], (bf16)aS[i][1], (bf16)aS[i][2], (bf16)aS[i][3] };
    *(bf16x4*)(Bx + obase + (p0 + i) * 64 + n0) = vb;
    *(bf16x4*)(states + obase + (p0 + i) * 64 + n0) = vs;
  }
}

// ---------------------------------------------------------------------------
// SSD stage 2: inclusive scan over chunks (f32 carry, bf16 storage).
__global__ __launch_bounds__(256) void ssd2_kernel(
    bf16* __restrict__ states, const float* __restrict__ dchunk)
{
  const int blk = blockIdx.x;  // 256 = b(2) x h(32) x q(4)
  const int b = blk >> 7, h = (blk >> 2) & 31, q = blk & 3;
  const int e0 = q * 1024 + threadIdx.x * 4;
  float fs0 = 0.f, fs1 = 0.f, fs2 = 0.f, fs3 = 0.f;
  #pragma unroll 1
  for (int c = 0; c < 64; ++c) {
    size_t idx = (((size_t)(b * 64 + c) * 32 + h) * 4096) + e0;
    float dec = dchunk[(b * 64 + c) * 32 + h];
    bf16x4 st = *(const bf16x4*)(states + idx);
    fs0 = fs0 * dec + (float)st[0]; fs1 = fs1 * dec + (float)st[1];
    fs2 = fs2 * dec + (float)st[2]; fs3 = fs3 * dec + (float)st[3];
    bf16x4 o = { (bf16)fs0, (bf16)fs1, (bf16)fs2, (bf16)fs3 };
    *(bf16x4*)(states + idx) = o;
  }
}

// ---------------------------------------------------------------------------
// SSD stage 3, one block per (b,c,h):
//   Y[l,p] = rowsum[l]*(C·Bx^T)[l,p] + expac[l]*(C·FS^T)[l,p] + D[h]*xsum[l]
//   proj cols [2048,4096) <- (bf16)(Y * silu(z))   (z from cols [0,2048))
__global__ __launch_bounds__(256) void ssd3_kernel(
    bf16* proj, const bf16* __restrict__ Bx, const bf16* __restrict__ FS,
    const float* __restrict__ rowsum, const float* __restrict__ expac,
    const float* __restrict__ xsum, const float* __restrict__ D_param)
{
  __shared__ float Cs[64][68], Bxs[64][68], FSs[64][68];
  __shared__ float rs_s[64], ea_s[64];
  const int blk = blockIdx.x;
  const int b = blk >> 11, c = (blk >> 5) & 63, h = blk & 31;
  const size_t bs0 = (size_t)b * 4096 + c * 64;
  const int tid = threadIdx.x;
  {
    int l = tid >> 2, q0 = (tid & 3) * 16;
    const bf16x8* csrc = (const bf16x8*)(proj + (bs0 + l) * 8192 + 6144 + h * 64 + q0);
    bf16x8 u0 = csrc[0], u1 = csrc[1];
    size_t mb = ((size_t)(b * 64 + c) * 32 + h) * 4096 + l * 64 + q0;
    const bf16x8* bx8 = (const bf16x8*)(Bx + mb);
    bf16x8 b0 = bx8[0], b1 = bx8[1];
    const bf16x8* fs8 = (const bf16x8*)(FS + mb);
    bf16x8 f0 = fs8[0], f1 = fs8[1];
    #pragma unroll
    for (int e = 0; e < 8; ++e) {
      Cs[l][q0 + e] = (float)u0[e];  Cs[l][q0 + 8 + e] = (float)u1[e];
      Bxs[l][q0 + e] = (float)b0[e]; Bxs[l][q0 + 8 + e] = (float)b1[e];
      FSs[l][q0 + e] = (float)f0[e]; FSs[l][q0 + 8 + e] = (float)f1[e];
    }
  }
  if (tid < 64) {
    int gidx = ((b * 64 + c) * 32 + h) * 64 + tid;
    rs_s[tid] = rowsum[gidx];
    ea_s[tid] = expac[gidx];
  }
  __syncthreads();
  const int l0 = (tid & 15) * 4, p0 = (tid >> 4) * 4;
  float a1[4][4] = {}, a2[4][4] = {};
  #pragma unroll 2
  for (int n = 0; n < 64; n += 4) {
    float4 cv[4], bx[4], fv[4];
    #pragma unroll
    for (int i = 0; i < 4; ++i) cv[i] = *(const float4*)&Cs[l0 + i][n];
    #pragma unroll
    for (int j = 0; j < 4; ++j) { bx[j] = *(const float4*)&Bxs[p0 + j][n]; fv[j] = *(const float4*)&FSs[p0 + j][n]; }
    #pragma unroll
    for (int i = 0; i < 4; ++i)
      #pragma unroll
      for (int j = 0; j < 4; ++j) {
        a1[i][j] += cv[i].x * bx[j].x + cv[i].y * bx[j].y + cv[i].z * bx[j].z + cv[i].w * bx[j].w;
        a2[i][j] += cv[i].x * fv[j].x + cv[i].y * fv[j].y + cv[i].z * fv[j].z + cv[i].w * fv[j].w;
      }
  }
  const float dpar = D_param[h];
  #pragma unroll
  for (int i = 0; i < 4; ++i) {
    int l = l0 + i;
    size_t bs = bs0 + l;
    float sk = dpar * xsum[bs * 32 + h];
    float r = rs_s[l], e = ea_s[l];
    #pragma unroll
    for (int j = 0; j < 4; ++j) {
      int p = p0 + j;
      float y = r * a1[i][j] + e * a2[i][j] + sk;
      float z = (float)proj[bs * 8192 + h * 64 + p];
      proj[bs * 8192 + 2048 + h * 64 + p] = (bf16)(y * z * sigmoid_f(z));
    }
  }
}

// ---------------------------------------------------------------------------
__global__ __launch_bounds__(256) void silu_mul_kernel(
    const bf16* __restrict__ gu, bf16* __restrict__ m)
{
  const size_t row = blockIdx.y;
  const int col2 = blockIdx.x * 256 + threadIdx.x;  // 0..1279
  const size_t gi = row * 5120 + col2 * 2;
  bf16x2 g = *(const bf16x2*)(gu + gi);
  bf16x2 u = *(const bf16x2*)(gu + gi + 2560);
  float g0 = (float)g[0], g1 = (float)g[1];
  float m0 = g0 * sigmoid_f(g0) * (float)u[0];
  float m1 = g1 * sigmoid_f(g1) * (float)u[1];
  bf16x2 mv = { (bf16)m0, (bf16)m1 };
  *(bf16x2*)(m + row * 2560 + col2 * 2) = mv;
}

// ---------------------------------------------------------------------------
extern "C" void kernel_launch(void* const* d_in, const int* in_sizes, int n_in,
                              void* d_out, int out_size, void* d_ws, size_t ws_size,
                              hipStream_t stream) {
  (void)in_sizes; (void)n_in; (void)out_size;
  if (ws_size < WS_NEEDED) return;  // diagnostic guard: fail absmax, not SIGABRT
  const float* x       = (const float*)d_in[0];
  const float* n1w     = (const float*)d_in[1];
  const float* n2w     = (const float*)d_in[2];
  const float* W_in    = (const float*)d_in[3];
  const float* W_out   = (const float*)d_in[4];
  const float* A_log   = (const float*)d_in[5];
  const float* D_param = (const float*)d_in[6];
  const float* dt_bias = (const float*)d_in[7];
  const float* B_bias  = (const float*)d_in[8];
  const float* C_bias  = (const float*)d_in[9];
  const float* Bn_w    = (const float*)d_in[10];
  const float* Cn_w    = (const float*)d_in[11];
  const float* Wg      = (const float*)d_in[12];
  const float* Wu      = (const float*)d_in[13];
  const float* Wd      = (const float*)d_in[14];
  float* out = (float*)d_out;
  char* ws = (char*)d_ws;

  bf16*  proj   = (bf16*)(ws + OFF_PROJ);
  float* projT  = (float*)(ws + OFF_PROJT);
  bf16*  h_hi   = (bf16*)(ws + OFF_HHI);
  bf16*  h_lo   = (bf16*)(ws + OFF_HLO);
  bf16*  Wt_in  = (bf16*)(ws + OFF_WTIN);
  bf16*  Wt_hi  = (bf16*)(ws + OFF_WTHI);
  bf16*  Wt_lo  = (bf16*)(ws + OFF_WTLO);
  bf16*  Wt_out = (bf16*)(ws + OFF_WTOUT);
  bf16*  Wt_gu  = (bf16*)(ws + OFF_WTGU);
  bf16*  Wt_d   = (bf16*)(ws + OFF_WTD);
  bf16*  Bx     = (bf16*)(ws + OFF_BX);
  bf16*  states = (bf16*)(ws + OFF_STATES);
  float* a_buf  = (float*)(ws + OFF_ABUF);
  float* xsum_  = (float*)(ws + OFF_XSUM);
  float* rowsum = (float*)(ws + OFF_ROWSUM);
  float* expac  = (float*)(ws + OFF_EXPA);
  float* dchunk = (float*)(ws + OFF_DCHUNK);
  float* Ssum   = (float*)(ws + OFF_HLO);    // 512KB chunk sums (h_lo dead by then)
  bf16*  ybf    = proj + 2048;               // cols [2048,4096) of proj, lda 8192
  bf16*  gubf   = (bf16*)(ws + OFF_GU);
  bf16*  mbf    = (bf16*)(ws + OFF_MBF);
  bf16*  h2bf   = h_hi;                      // reuse after proj GEMMs
  float* x2     = out;                       // x2 lives in d_out

  // --- weight transposes needed up-front ---
  transpose_cast<<<dim3(256, 32), 256, 0, stream>>>(W_in, 9248, 0, Wt_in, 1024, 8192);
  transpose_cast_hilo<<<dim3(36, 32), 256, 0, stream>>>(W_in, 9248, 8192, Wt_hi, Wt_lo, 1024, 1056);

  // --- norm1 (hi/lo split for the precision-critical dt/theta tail GEMM) ---
  rmsnorm_kernel<<<8192, 256, 0, stream>>>(x, n1w, h_hi, h_lo);

  // --- in-projection ---
  gemm_bt<1><<<dim3(64, 64), 256, 0, stream>>>(h_hi, Wt_in, proj, nullptr, 1024, 1024, 8192);
  gemm_bt<0><<<dim3(9, 64), 256, 0, stream>>>(h_hi, Wt_hi, projT, nullptr, 1024, 1024, 1152);
  gemm_bt<3><<<dim3(9, 64), 256, 0, stream>>>(h_hi, Wt_lo, projT, nullptr, 1024, 1024, 1152);
  gemm_bt<3><<<dim3(9, 64), 256, 0, stream>>>(h_lo, Wt_hi, projT, nullptr, 1024, 1024, 1152);

  // --- per-token/head prep (in place) + hierarchical RoPE ---
  prep_kernel<<<8192, 256, 0, stream>>>(proj, projT, A_log, dt_bias, B_bias, C_bias,
                                        Bn_w, Cn_w, a_buf, xsum_);
  chunk_sum_kernel<<<128, 256, 0, stream>>>(projT, Ssum);
  rope_kernel<<<4096, 256, 0, stream>>>(proj, projT, Ssum);

  // --- SSD ---
  ssd1_kernel<<<4096, 256, 0, stream>>>(proj, a_buf, Bx, states, rowsum, expac, dchunk);
  ssd2_kernel<<<256, 256, 0, stream>>>(states, dchunk);
  ssd3_kernel<<<4096, 256, 0, stream>>>(proj, Bx, states, rowsum, expac, xsum_, D_param);

  // --- late weight transposes (overlay dead states region) ---
  transpose_cast<<<dim3(32, 64), 256, 0, stream>>>(W_out, 1024, 0, Wt_out, 2048, 1024);
  transpose_cast<<<dim3(80, 32), 256, 0, stream>>>(Wg, 2560, 0, Wt_gu, 1024, 2560);
  transpose_cast<<<dim3(80, 32), 256, 0, stream>>>(Wu, 2560, 0, Wt_gu + (size_t)2560 * 1024, 1024, 2560);
  transpose_cast<<<dim3(32, 80), 256, 0, stream>>>(Wd, 1024, 0, Wt_d, 2560, 1024);

  // --- out-projection + residual (x2 -> d_out) ---
  gemm_bt<2><<<dim3(8, 64), 256, 0, stream>>>(ybf, Wt_out, x2, x, 2048, 8192, 1024);

  // --- MLP ---
  rmsnorm_kernel<<<8192, 256, 0, stream>>>(x2, n2w, h2bf, nullptr);
  gemm_bt<1><<<dim3(40, 64), 256, 0, stream>>>(h2bf, Wt_gu, gubf, nullptr, 1024, 1024, 5120);
  silu_mul_kernel<<<dim3(5, 8192), 256, 0, stream>>>(gubf, mbf);
  gemm_bt<2><<<dim3(8, 64), 256, 0, stream>>>(mbf, Wt_d, out, x2, 2560, 2560, 1024);
}

// Round 5
// 948.443 us; speedup vs baseline: 1.3472x; 1.1191x over previous
//
#include <hip/hip_runtime.h>
#include <cstdint>
#include <cmath>

// ---------------------------------------------------------------------------
// Mamba3 block forward, MI355X (gfx950).
// B=2, S=4096 (8192 tokens), D_MODEL=1024, D_INNER=2048, NHEADS=32, HD=64,
// D_STATE=64, CHUNK=64, D_MLP=2560, PROJ=9248.
// Workspace budget: 250.5 MiB. x2 lives in d_out.
// ---------------------------------------------------------------------------

typedef __bf16 bf16;
typedef __bf16 bf16x2 __attribute__((ext_vector_type(2)));
typedef __bf16 bf16x4 __attribute__((ext_vector_type(4)));
typedef __bf16 bf16x8 __attribute__((ext_vector_type(8)));
typedef float fx4 __attribute__((ext_vector_type(4)));

#define DEV __device__ __forceinline__

// ---- workspace layout (bytes) ---------------------------------------------
// proj (bf16 8192x8192): cols z[0,2048) xs->xg->ybf[2048,4096) B[4096,6144) C[6144,8192)
//   later: gu (8192x5120 bf16) at +0 ; m (8192x2560 bf16) at +83886080
#define OFF_PROJ    0ull
#define OFF_HHI     134217728ull   // 8192x1024 bf16 (h hi) ; later h2_bf
#define OFF_HLO     150994944ull   // 8192x1024 bf16 (h lo) ; later S (chunk sums, 512KB)
#define OFF_WTIN    167772160ull   // 8192x1024 bf16
#define OFF_WTHI    184549376ull   // 1152x1024 bf16
#define OFF_WTLO    186908672ull   // 1152x1024 bf16
#define OFF_PROJT   189267968ull   // 8192x1152 f32 (dt,theta) -- dead after rope
#define OFF_BX      189267968ull   // 4096x4096 bf16 (written at ssd1, overlays projT)
#define OFF_STATES  222822400ull   // 4096x4096 bf16 -> FS in place; dead after ssd3
#define OFF_WTOUT   222822400ull   // 1024x2048 bf16 (after ssd3, overlays states)
#define OFF_WTGU    227016704ull   // 5120x1024 bf16 (after ssd3)
#define OFF_WTD     237502464ull   // 1024x2560 bf16 (after ssd3)
#define OFF_ABUF    256376832ull   // 8192x32 f32 (per-token A)
#define OFF_XSUM    257425408ull   // 8192x32 f32
#define OFF_ROWSUM  258473984ull   // (2,64,32,64) f32
#define OFF_EXPA    260571136ull   // (2,64,32,64) f32
#define OFF_DCHUNK  262668288ull   // (2,64,32) f32
#define WS_NEEDED   262684672ull

#define OFF_GU      0ull
#define OFF_MBF     83886080ull

// ---------------------------------------------------------------------------
DEV void async_copy16(void* lds, const void* gptr) {
  __builtin_amdgcn_global_load_lds(
      (const __attribute__((address_space(1))) unsigned int*)(gptr),
      (__attribute__((address_space(3))) unsigned int*)(lds),
      16, 0, 0);
}

DEV float warp_sum64(float v) {
  #pragma unroll
  for (int o = 32; o; o >>= 1) v += __shfl_xor(v, o);
  return v;
}

DEV float softplus_f(float x) { return x > 20.f ? x : log1pf(expf(x)); }
DEV float sigmoid_f(float x) { return 1.f / (1.f + expf(-x)); }

// ---------------------------------------------------------------------------
// Transpose + cast fp32 (RxC slice, row stride ld, col offset col0) -> bf16 (Cp x R)
__global__ __launch_bounds__(256) void transpose_cast(
    const float* __restrict__ src, int ld, int col0,
    bf16* __restrict__ dst, int R, int C)
{
  __shared__ float tile[32][33];
  const int c0 = blockIdx.x * 32, r0 = blockIdx.y * 32;
  const int tx = threadIdx.x & 31, ty = threadIdx.x >> 5;
  #pragma unroll
  for (int ii = 0; ii < 4; ++ii) {
    int i = ty + ii * 8;
    int c = c0 + tx;
    tile[i][tx] = (c < C) ? src[(size_t)(r0 + i) * ld + col0 + c] : 0.f;
  }
  __syncthreads();
  #pragma unroll
  for (int ii = 0; ii < 4; ++ii) {
    int i = ty + ii * 8;
    dst[(size_t)(c0 + i) * R + r0 + tx] = (bf16)tile[tx][i];
  }
}

__global__ __launch_bounds__(256) void transpose_cast_hilo(
    const float* __restrict__ src, int ld, int col0,
    bf16* __restrict__ dhi, bf16* __restrict__ dlo, int R, int C)
{
  __shared__ float tile[32][33];
  const int c0 = blockIdx.x * 32, r0 = blockIdx.y * 32;
  const int tx = threadIdx.x & 31, ty = threadIdx.x >> 5;
  #pragma unroll
  for (int ii = 0; ii < 4; ++ii) {
    int i = ty + ii * 8;
    int c = c0 + tx;
    tile[i][tx] = (c < C) ? src[(size_t)(r0 + i) * ld + col0 + c] : 0.f;
  }
  __syncthreads();
  #pragma unroll
  for (int ii = 0; ii < 4; ++ii) {
    int i = ty + ii * 8;
    float v = tile[tx][i];
    bf16 hi = (bf16)v;
    size_t o = (size_t)(c0 + i) * R + r0 + tx;
    dhi[o] = hi;
    dlo[o] = (bf16)(v - (float)hi);
  }
}

// ---------------------------------------------------------------------------
__global__ __launch_bounds__(256) void rmsnorm_kernel(
    const float* __restrict__ x, const float* __restrict__ w,
    bf16* __restrict__ hi, bf16* __restrict__ lo)
{
  __shared__ float red[4];
  const size_t row = blockIdx.x;
  const int tid = threadIdx.x;
  float4 v = ((const float4*)(x + row * 1024))[tid];
  float ss = v.x * v.x + v.y * v.y + v.z * v.z + v.w * v.w;
  ss = warp_sum64(ss);
  if ((tid & 63) == 0) red[tid >> 6] = ss;
  __syncthreads();
  float tot = red[0] + red[1] + red[2] + red[3];
  float s = rsqrtf(tot * (1.f / 1024.f) + 1e-5f);
  float4 wv = ((const float4*)w)[tid];
  float h0 = v.x * s * wv.x, h1 = v.y * s * wv.y, h2 = v.z * s * wv.z, h3 = v.w * s * wv.w;
  bf16x4 hv = { (bf16)h0, (bf16)h1, (bf16)h2, (bf16)h3 };
  *(bf16x4*)(hi + row * 1024 + tid * 4) = hv;
  if (lo) {
    bf16x4 lv = { (bf16)(h0 - (float)hv[0]), (bf16)(h1 - (float)hv[1]),
                  (bf16)(h2 - (float)hv[2]), (bf16)(h3 - (float)hv[3]) };
    *(bf16x4*)(lo + row * 1024 + tid * 4) = lv;
  }
}

// ---------------------------------------------------------------------------
// bf16 GEMM, A(MxK) row stride lda, B(NxK) row-major (B^T of KxN), out MxN.
// 128x128 tile, BK=64, 4 waves, 16x16x32 MFMA, global_load_lds staging,
// XOR-swizzled LDS. MODE: 0=f32 store, 1=bf16 store, 2=f32 v+resid, 3=f32 +=
template <int MODE>
__global__ __launch_bounds__(256) void gemm_bt(
    const bf16* A, const bf16* B, void* Cout, const float* resid,
    int K, int lda, int ldc)
{
  __shared__ bf16 As[128 * 64];
  __shared__ bf16 Bs[128 * 64];
  const int tid = threadIdx.x, wid = tid >> 6, lane = tid & 63;
  const int m0 = blockIdx.y * 128, n0 = blockIdx.x * 128;
  const int wm = (wid & 1) * 64, wn = (wid >> 1) * 64;
  fx4 acc[4][4];
  #pragma unroll
  for (int i = 0; i < 4; ++i)
    #pragma unroll
    for (int j = 0; j < 4; ++j) { fx4 z = {0.f, 0.f, 0.f, 0.f}; acc[i][j] = z; }

  const int srow = wid * 32 + (lane >> 3);
  const int slot = lane & 7;

  for (int k0 = 0; k0 < K; k0 += 64) {
    __syncthreads();
    #pragma unroll
    for (int i = 0; i < 4; ++i) {
      int m = srow + i * 8;
      int cA = ((slot ^ (m & 7)) * 8);
      async_copy16(&As[wid * 2048 + i * 512], A + (size_t)(m0 + m) * lda + k0 + cA);
    }
    #pragma unroll
    for (int i = 0; i < 4; ++i) {
      int n = srow + i * 8;
      int cB = ((slot ^ (n & 7)) * 8);
      async_copy16(&Bs[wid * 2048 + i * 512], B + (size_t)(n0 + n) * K + k0 + cB);
    }
    __syncthreads();
    #pragma unroll
    for (int kk = 0; kk < 2; ++kk) {
      bf16x8 af[4], bfr[4];
      #pragma unroll
      for (int i = 0; i < 4; ++i) {
        int mm = wm + i * 16 + (lane & 15);
        int sA = (kk * 4 + (lane >> 4)) ^ (mm & 7);
        af[i] = *(const bf16x8*)&As[mm * 64 + sA * 8];
        int nn = wn + i * 16 + (lane & 15);
        int sB = (kk * 4 + (lane >> 4)) ^ (nn & 7);
        bfr[i] = *(const bf16x8*)&Bs[nn * 64 + sB * 8];
      }
      #pragma unroll
      for (int i = 0; i < 4; ++i)
        #pragma unroll
        for (int j = 0; j < 4; ++j)
          acc[i][j] = __builtin_amdgcn_mfma_f32_16x16x32_bf16(af[i], bfr[j], acc[i][j], 0, 0, 0);
    }
  }
  // C/D layout: col=lane&15, row=(lane>>4)*4+reg
  const int r0 = (lane >> 4) * 4, cc = lane & 15;
  #pragma unroll
  for (int i = 0; i < 4; ++i) {
    #pragma unroll
    for (int j = 0; j < 4; ++j) {
      #pragma unroll
      for (int r = 0; r < 4; ++r) {
        int m = m0 + wm + i * 16 + r0 + r;
        int n = n0 + wn + j * 16 + cc;
        size_t off = (size_t)m * ldc + n;
        float v = acc[i][j][r];
        if (MODE == 0) ((float*)Cout)[off] = v;
        else if (MODE == 1) ((bf16*)Cout)[off] = (bf16)v;
        else if (MODE == 2) ((float*)Cout)[off] = v + resid[off];
        else ((float*)Cout)[off] += v;
      }
    }
  }
}

// ---------------------------------------------------------------------------
// Per (token, head), IN PLACE on proj (stride 8192):
//   xg = xs*gamma at cols [2048,4096); B' = rms(B)+bias at [4096,6144);
//   C' = rms(C)+bias at [6144,8192); dt written back into projT col h.
__global__ __launch_bounds__(256) void prep_kernel(
    bf16* proj, float* projT,
    const float* __restrict__ A_log, const float* __restrict__ dt_bias,
    const float* __restrict__ B_bias, const float* __restrict__ C_bias,
    const float* __restrict__ Bn_w, const float* __restrict__ Cn_w,
    float* __restrict__ a_buf, float* __restrict__ xsum)
{
  const size_t bs = blockIdx.x;
  const int w = threadIdx.x >> 6, lane = threadIdx.x & 63;
  bf16* prow = proj + bs * 8192;
  float* trow = projT + bs * 1152;
  #pragma unroll 1
  for (int hh = 0; hh < 8; ++hh) {
    const int h = w * 8 + hh;
    float dtr = trow[h] + dt_bias[h];
    float dt = softplus_f(dtr);
    float a = -expf(A_log[h]) * dt;
    float alpha = expf(a);
    float gamma = (alpha - 1.f) / (a + 1e-6f) * 0.5f + 1.f;

    float xv = (float)prow[2048 + h * 64 + lane];
    float sx = warp_sum64(xv);
    prow[2048 + h * 64 + lane] = (bf16)(xv * gamma);
    if (lane == 0) { a_buf[bs * 32 + h] = a; xsum[bs * 32 + h] = sx; trow[h] = dt; }

    float bv = (float)prow[4096 + h * 64 + lane];
    float sb = warp_sum64(bv * bv);
    prow[4096 + h * 64 + lane] =
        (bf16)(bv * rsqrtf(sb * (1.f / 64.f) + 1e-5f) * Bn_w[lane] + B_bias[h * 64 + lane]);

    float cv = (float)prow[6144 + h * 64 + lane];
    float sc = warp_sum64(cv * cv);
    prow[6144 + h * 64 + lane] =
        (bf16)(cv * rsqrtf(sc * (1.f / 64.f) + 1e-5f) * Cn_w[lane] + C_bias[h * 64 + lane]);
  }
}

// ---------------------------------------------------------------------------
// Chunk sums of dt*theta: S[(b*64+c)][h*32+d] = sum_{t in chunk} dt[t][h]*theta[t][h][d]
__global__ __launch_bounds__(256) void chunk_sum_kernel(
    const float* __restrict__ projT, float* __restrict__ S)
{
  __shared__ float lds[8448];   // 8 rows x 1056 cols
  const int blk = blockIdx.x;                 // b*64 + c
  const size_t row0 = (size_t)blk * 64;
  const int tid = threadIdx.x;
  float s[4] = {0.f, 0.f, 0.f, 0.f};
  #pragma unroll 1
  for (int batch = 0; batch < 8; ++batch) {
    __syncthreads();
    const float* src = projT + (row0 + batch * 8) * 1152;
    #pragma unroll
    for (int i = 0; i < 33; ++i) {
      int idx = i * 256 + tid;
      int r = idx / 1056, col = idx - r * 1056;
      lds[idx] = src[r * 1152 + col];
    }
    __syncthreads();
    #pragma unroll
    for (int k = 0; k < 4; ++k) {
      int hd = tid + 256 * k;
      int h = hd >> 5, d = hd & 31;
      #pragma unroll
      for (int r = 0; r < 8; ++r)
        s[k] += lds[r * 1056 + h] * lds[r * 1056 + 32 + h * 32 + d];
    }
  }
  #pragma unroll
  for (int k = 0; k < 4; ++k)
    S[(size_t)blk * 1024 + tid + 256 * k] = s[k];
}

// ---------------------------------------------------------------------------
// RoPE apply, one block per (b,c,h).
__global__ __launch_bounds__(256) void rope_kernel(
    bf16* proj, const float* __restrict__ projT, const float* __restrict__ S)
{
  __shared__ float angs[64 * 33], angc[64 * 33];
  const int blk = blockIdx.x;
  const int b = blk >> 11, c = (blk >> 5) & 63, h = blk & 31;
  const size_t t0 = (size_t)b * 4096 + c * 64;
  const int w = threadIdx.x >> 6, lane = threadIdx.x & 63;
  const float* tr = projT + (t0 + lane) * 1152;
  float dtv = tr[h];
  const float* thp = tr + 32 + h * 32 + w * 8;
  float4 th0 = *(const float4*)thp;
  float4 th1 = *(const float4*)(thp + 4);
  const float* Sp = S + (size_t)(b * 64 + lane) * 1024 + h * 32 + w * 8;
  float4 S0 = *(const float4*)Sp;
  float4 S1 = *(const float4*)(Sp + 4);
  float th[8] = { th0.x, th0.y, th0.z, th0.w, th1.x, th1.y, th1.z, th1.w };
  float Sv[8] = { S0.x, S0.y, S0.z, S0.w, S1.x, S1.y, S1.z, S1.w };
  #pragma unroll 1
  for (int j = 0; j < 8; ++j) {
    int d = w * 8 + j;
    float sv = (lane < c) ? Sv[j] : 0.f;
    float off = warp_sum64(sv);
    float v = dtv * th[j];
    #pragma unroll
    for (int o = 1; o < 64; o <<= 1) { float u = __shfl_up(v, o); if (lane >= o) v += u; }
    float ang = off + v;
    float sn, cs;
    sincosf(ang, &sn, &cs);
    angs[lane * 33 + d] = sn;
    angc[lane * 33 + d] = cs;
  }
  __syncthreads();
  const int tt = threadIdx.x >> 2, q = threadIdx.x & 3;
  const size_t base = (t0 + tt) * 8192 + 4096 + h * 64 + q * 16;
  #pragma unroll
  for (int m = 0; m < 2; ++m) {   // m=0: B, m=1: C
    bf16* p = proj + base + m * 2048;
    bf16x8 v0 = *(const bf16x8*)(p);
    bf16x8 v1 = *(const bf16x8*)(p + 8);
    bf16x8 r0, r1;
    #pragma unroll
    for (int pp = 0; pp < 4; ++pp) {
      int d = q * 8 + pp;
      float e1 = (float)v0[2 * pp], e2 = (float)v0[2 * pp + 1];
      float sn = angs[tt * 33 + d], cs = angc[tt * 33 + d];
      r0[2 * pp]     = (bf16)(cs * e1 - sn * e2);
      r0[2 * pp + 1] = (bf16)(sn * e1 + cs * e2);
    }
    #pragma unroll
    for (int pp = 0; pp < 4; ++pp) {
      int d = q * 8 + 4 + pp;
      float e1 = (float)v1[2 * pp], e2 = (float)v1[2 * pp + 1];
      float sn = angs[tt * 33 + d], cs = angc[tt * 33 + d];
      r1[2 * pp]     = (bf16)(cs * e1 - sn * e2);
      r1[2 * pp + 1] = (bf16)(sn * e1 + cs * e2);
    }
    *(bf16x8*)(p) = r0;
    *(bf16x8*)(p + 8) = r1;
  }
}

// ---------------------------------------------------------------------------
// SSD stage 1 (MFMA), one block per (b,c,h) with blk = b*2048+c*32+h:
//   Bx[p,n] = sum_l x[l,p]B[l,n];  states[p,n] = sum_l dsv[l] x[l,p] B[l,n]
// A/B fragments read transposed (scalar u16) from LDS tiles [l][72].
__global__ __launch_bounds__(256) void ssd1_kernel(
    const bf16* __restrict__ proj, const float* __restrict__ a_buf,
    bf16* __restrict__ Bx, bf16* __restrict__ states,
    float* __restrict__ rowsum, float* __restrict__ expac, float* __restrict__ dchunk)
{
  __shared__ bf16 Xs[64 * 72], Bs[64 * 72];
  __shared__ float acum[64], dsv[64];
  const int blk = blockIdx.x;
  const int h = blk & 31;
  const size_t bs0 = ((size_t)(blk >> 5)) * 64;   // b*4096 + c*64
  const int tid = threadIdx.x;
  const int l = tid >> 2, p0 = (tid & 3) * 16;
  {
    const bf16* xrow = proj + (bs0 + l) * 8192 + 2048 + h * 64 + p0;
    *(bf16x8*)&Xs[l * 72 + p0]     = ((const bf16x8*)xrow)[0];
    *(bf16x8*)&Xs[l * 72 + p0 + 8] = ((const bf16x8*)xrow)[1];
    const bf16* brow = proj + (bs0 + l) * 8192 + 4096 + h * 64 + p0;
    *(bf16x8*)&Bs[l * 72 + p0]     = ((const bf16x8*)brow)[0];
    *(bf16x8*)&Bs[l * 72 + p0 + 8] = ((const bf16x8*)brow)[1];
  }
  if (tid < 64) {
    float v = a_buf[(bs0 + tid) * 32 + h];
    #pragma unroll
    for (int o = 1; o < 64; o <<= 1) { float u = __shfl_up(v, o); if (tid >= o) v += u; }
    acum[tid] = v;
    float a63 = __shfl(v, 63);
    dsv[tid] = expf(a63 - v);
    expac[(size_t)blk * 64 + tid] = expf(v);
    if (tid == 63) dchunk[blk] = expf(v);
  }
  __syncthreads();
  // rowsum[l] = sum_{s<=l} exp(acum[l]-acum[s]) + (63-l), 4 threads per l
  {
    float al = acum[l];
    float rs = 0.f;
    for (int s = tid & 3; s <= l; s += 4) rs += expf(al - acum[s]);
    rs += __shfl_xor(rs, 1);
    rs += __shfl_xor(rs, 2);
    if ((tid & 3) == 0) rowsum[(size_t)blk * 64 + l] = rs + (float)(63 - l);
  }
  // MFMA phase
  const int wv = tid >> 6, lane = tid & 63;
  const int mi = lane & 15, kq = lane >> 4;
  const int m0 = wv * 16;   // p-tile
  fx4 accB[4], accS[4];
  #pragma unroll
  for (int j4 = 0; j4 < 4; ++j4) { fx4 z = {0.f,0.f,0.f,0.f}; accB[j4] = z; accS[j4] = z; }
  #pragma unroll
  for (int kk = 0; kk < 2; ++kk) {
    const int lb = kk * 32 + kq * 8;
    bf16x8 aX, aXd;
    #pragma unroll
    for (int j = 0; j < 8; ++j) {
      bf16 xv = Xs[(lb + j) * 72 + m0 + mi];
      aX[j] = xv;
      aXd[j] = (bf16)((float)xv * dsv[lb + j]);
    }
    #pragma unroll
    for (int j4 = 0; j4 < 4; ++j4) {
      bf16x8 bB;
      #pragma unroll
      for (int j = 0; j < 8; ++j) bB[j] = Bs[(lb + j) * 72 + j4 * 16 + mi];
      accB[j4] = __builtin_amdgcn_mfma_f32_16x16x32_bf16(aX, bB, accB[j4], 0, 0, 0);
      accS[j4] = __builtin_amdgcn_mfma_f32_16x16x32_bf16(aXd, bB, accS[j4], 0, 0, 0);
    }
  }
  const size_t obase = (size_t)blk * 4096;
  #pragma unroll
  for (int j4 = 0; j4 < 4; ++j4) {
    #pragma unroll
    for (int r = 0; r < 4; ++r) {
      int p = m0 + kq * 4 + r;
      int n = j4 * 16 + mi;
      Bx[obase + p * 64 + n] = (bf16)accB[j4][r];
      states[obase + p * 64 + n] = (bf16)accS[j4][r];
    }
  }
}

// ---------------------------------------------------------------------------
// SSD stage 2: inclusive scan over chunks (f32 carry, bf16 storage).
__global__ __launch_bounds__(128) void ssd2_kernel(
    bf16* __restrict__ states, const float* __restrict__ dchunk)
{
  const int blk = blockIdx.x;  // 512 = b(2) x h(32) x q(8)
  const int b = blk >> 8, h = (blk >> 3) & 31, q = blk & 7;
  const int e0 = q * 512 + threadIdx.x * 4;
  float fs0 = 0.f, fs1 = 0.f, fs2 = 0.f, fs3 = 0.f;
  #pragma unroll 2
  for (int c = 0; c < 64; ++c) {
    size_t idx = ((size_t)(b * 2048 + c * 32 + h) * 4096) + e0;
    float dec = dchunk[b * 2048 + c * 32 + h];
    bf16x4 st = *(const bf16x4*)(states + idx);
    fs0 = fs0 * dec + (float)st[0]; fs1 = fs1 * dec + (float)st[1];
    fs2 = fs2 * dec + (float)st[2]; fs3 = fs3 * dec + (float)st[3];
    bf16x4 o = { (bf16)fs0, (bf16)fs1, (bf16)fs2, (bf16)fs3 };
    *(bf16x4*)(states + idx) = o;
  }
}

// ---------------------------------------------------------------------------
// SSD stage 3 (MFMA), one block per (b,c,h):
//   Y[l,p] = rowsum[l]*(C·Bx^T)[l,p] + expac[l]*(C·FS^T)[l,p] + D[h]*xsum[l]
//   proj cols [2048,4096) <- (bf16)(Y * silu(z)), z from cols [0,2048)
// Both contractions are over n -> fragments are natural row-major vector reads.
__global__ __launch_bounds__(256) void ssd3_kernel(
    bf16* proj, const bf16* __restrict__ Bx, const bf16* __restrict__ FS,
    const float* __restrict__ rowsum, const float* __restrict__ expac,
    const float* __restrict__ xsum, const float* __restrict__ D_param)
{
  __shared__ bf16 Cs[64 * 72], BxS[64 * 72], FSs[64 * 72];
  __shared__ float rs_s[64], ea_s[64], sk_s[64];
  const int blk = blockIdx.x;
  const int h = blk & 31;
  const size_t bs0 = ((size_t)(blk >> 5)) * 64;
  const int tid = threadIdx.x;
  const int l = tid >> 2, q0 = (tid & 3) * 16;
  {
    const bf16* crow = proj + (bs0 + l) * 8192 + 6144 + h * 64 + q0;
    *(bf16x8*)&Cs[l * 72 + q0]     = ((const bf16x8*)crow)[0];
    *(bf16x8*)&Cs[l * 72 + q0 + 8] = ((const bf16x8*)crow)[1];
    size_t mb = (size_t)blk * 4096 + l * 64 + q0;   // row p=l of Bx/FS
    *(bf16x8*)&BxS[l * 72 + q0]     = ((const bf16x8*)(Bx + mb))[0];
    *(bf16x8*)&BxS[l * 72 + q0 + 8] = ((const bf16x8*)(Bx + mb))[1];
    *(bf16x8*)&FSs[l * 72 + q0]     = ((const bf16x8*)(FS + mb))[0];
    *(bf16x8*)&FSs[l * 72 + q0 + 8] = ((const bf16x8*)(FS + mb))[1];
  }
  if (tid < 64) {
    rs_s[tid] = rowsum[(size_t)blk * 64 + tid];
    ea_s[tid] = expac[(size_t)blk * 64 + tid];
    sk_s[tid] = D_param[h] * xsum[(bs0 + tid) * 32 + h];
  }
  __syncthreads();
  const int wv = tid >> 6, lane = tid & 63;
  const int mi = lane & 15, kq = lane >> 4;
  const int m0 = wv * 16;   // l-tile
  fx4 acc1[4], acc2[4];
  #pragma unroll
  for (int j4 = 0; j4 < 4; ++j4) { fx4 z = {0.f,0.f,0.f,0.f}; acc1[j4] = z; acc2[j4] = z; }
  #pragma unroll
  for (int kk = 0; kk < 2; ++kk) {
    bf16x8 aC = *(const bf16x8*)&Cs[(m0 + mi) * 72 + kk * 32 + kq * 8];
    #pragma unroll
    for (int j4 = 0; j4 < 4; ++j4) {
      bf16x8 bx = *(const bf16x8*)&BxS[(j4 * 16 + mi) * 72 + kk * 32 + kq * 8];
      bf16x8 fs = *(const bf16x8*)&FSs[(j4 * 16 + mi) * 72 + kk * 32 + kq * 8];
      acc1[j4] = __builtin_amdgcn_mfma_f32_16x16x32_bf16(aC, bx, acc1[j4], 0, 0, 0);
      acc2[j4] = __builtin_amdgcn_mfma_f32_16x16x32_bf16(aC, fs, acc2[j4], 0, 0, 0);
    }
  }
  #pragma unroll
  for (int j4 = 0; j4 < 4; ++j4) {
    #pragma unroll
    for (int r = 0; r < 4; ++r) {
      int li = m0 + kq * 4 + r;
      int p = j4 * 16 + mi;
      float y = rs_s[li] * acc1[j4][r] + ea_s[li] * acc2[j4][r] + sk_s[li];
      size_t zoff = (bs0 + li) * 8192 + h * 64 + p;
      float z = (float)proj[zoff];
      proj[zoff + 2048] = (bf16)(y * z * sigmoid_f(z));
    }
  }
}

// ---------------------------------------------------------------------------
__global__ __launch_bounds__(256) void silu_mul_kernel(
    const bf16* __restrict__ gu, bf16* __restrict__ m)
{
  const size_t row = blockIdx.y;
  const int col2 = blockIdx.x * 256 + threadIdx.x;  // 0..1279
  const size_t gi = row * 5120 + col2 * 2;
  bf16x2 g = *(const bf16x2*)(gu + gi);
  bf16x2 u = *(const bf16x2*)(gu + gi + 2560);
  float g0 = (float)g[0], g1 = (float)g[1];
  float m0 = g0 * sigmoid_f(g0) * (float)u[0];
  float m1 = g1 * sigmoid_f(g1) * (float)u[1];
  bf16x2 mv = { (bf16)m0, (bf16)m1 };
  *(bf16x2*)(m + row * 2560 + col2 * 2) = mv;
}

// ---------------------------------------------------------------------------
extern "C" void kernel_launch(void* const* d_in, const int* in_sizes, int n_in,
                              void* d_out, int out_size, void* d_ws, size_t ws_size,
                              hipStream_t stream) {
  (void)in_sizes; (void)n_in; (void)out_size;
  if (ws_size < WS_NEEDED) return;  // diagnostic guard: fail absmax, not SIGABRT
  const float* x       = (const float*)d_in[0];
  const float* n1w     = (const float*)d_in[1];
  const float* n2w     = (const float*)d_in[2];
  const float* W_in    = (const float*)d_in[3];
  const float* W_out   = (const float*)d_in[4];
  const float* A_log   = (const float*)d_in[5];
  const float* D_param = (const float*)d_in[6];
  const float* dt_bias = (const float*)d_in[7];
  const float* B_bias  = (const float*)d_in[8];
  const float* C_bias  = (const float*)d_in[9];
  const float* Bn_w    = (const float*)d_in[10];
  const float* Cn_w    = (const float*)d_in[11];
  const float* Wg      = (const float*)d_in[12];
  const float* Wu      = (const float*)d_in[13];
  const float* Wd      = (const float*)d_in[14];
  float* out = (float*)d_out;
  char* ws = (char*)d_ws;

  bf16*  proj   = (bf16*)(ws + OFF_PROJ);
  float* projT  = (float*)(ws + OFF_PROJT);
  bf16*  h_hi   = (bf16*)(ws + OFF_HHI);
  bf16*  h_lo   = (bf16*)(ws + OFF_HLO);
  bf16*  Wt_in  = (bf16*)(ws + OFF_WTIN);
  bf16*  Wt_hi  = (bf16*)(ws + OFF_WTHI);
  bf16*  Wt_lo  = (bf16*)(ws + OFF_WTLO);
  bf16*  Wt_out = (bf16*)(ws + OFF_WTOUT);
  bf16*  Wt_gu  = (bf16*)(ws + OFF_WTGU);
  bf16*  Wt_d   = (bf16*)(ws + OFF_WTD);
  bf16*  Bx     = (bf16*)(ws + OFF_BX);
  bf16*  states = (bf16*)(ws + OFF_STATES);
  float* a_buf  = (float*)(ws + OFF_ABUF);
  float* xsum_  = (float*)(ws + OFF_XSUM);
  float* rowsum = (float*)(ws + OFF_ROWSUM);
  float* expac  = (float*)(ws + OFF_EXPA);
  float* dchunk = (float*)(ws + OFF_DCHUNK);
  float* Ssum   = (float*)(ws + OFF_HLO);    // 512KB chunk sums (h_lo dead by then)
  bf16*  ybf    = proj + 2048;               // cols [2048,4096) of proj, lda 8192
  bf16*  gubf   = (bf16*)(ws + OFF_GU);
  bf16*  mbf    = (bf16*)(ws + OFF_MBF);
  bf16*  h2bf   = h_hi;                      // reuse after proj GEMMs
  float* x2     = out;                       // x2 lives in d_out

  // --- weight transposes needed up-front ---
  transpose_cast<<<dim3(256, 32), 256, 0, stream>>>(W_in, 9248, 0, Wt_in, 1024, 8192);
  transpose_cast_hilo<<<dim3(36, 32), 256, 0, stream>>>(W_in, 9248, 8192, Wt_hi, Wt_lo, 1024, 1056);

  // --- norm1 (hi/lo split for the precision-critical dt/theta tail GEMM) ---
  rmsnorm_kernel<<<8192, 256, 0, stream>>>(x, n1w, h_hi, h_lo);

  // --- in-projection ---
  gemm_bt<1><<<dim3(64, 64), 256, 0, stream>>>(h_hi, Wt_in, proj, nullptr, 1024, 1024, 8192);
  gemm_bt<0><<<dim3(9, 64), 256, 0, stream>>>(h_hi, Wt_hi, projT, nullptr, 1024, 1024, 1152);
  gemm_bt<3><<<dim3(9, 64), 256, 0, stream>>>(h_hi, Wt_lo, projT, nullptr, 1024, 1024, 1152);
  gemm_bt<3><<<dim3(9, 64), 256, 0, stream>>>(h_lo, Wt_hi, projT, nullptr, 1024, 1024, 1152);

  // --- per-token/head prep (in place) + hierarchical RoPE ---
  prep_kernel<<<8192, 256, 0, stream>>>(proj, projT, A_log, dt_bias, B_bias, C_bias,
                                        Bn_w, Cn_w, a_buf, xsum_);
  chunk_sum_kernel<<<128, 256, 0, stream>>>(projT, Ssum);
  rope_kernel<<<4096, 256, 0, stream>>>(proj, projT, Ssum);

  // --- SSD (MFMA) ---
  ssd1_kernel<<<4096, 256, 0, stream>>>(proj, a_buf, Bx, states, rowsum, expac, dchunk);
  ssd2_kernel<<<512, 128, 0, stream>>>(states, dchunk);
  ssd3_kernel<<<4096, 256, 0, stream>>>(proj, Bx, states, rowsum, expac, xsum_, D_param);

  // --- late weight transposes (overlay dead states region) ---
  transpose_cast<<<dim3(32, 64), 256, 0, stream>>>(W_out, 1024, 0, Wt_out, 2048, 1024);
  transpose_cast<<<dim3(80, 32), 256, 0, stream>>>(Wg, 2560, 0, Wt_gu, 1024, 2560);
  transpose_cast<<<dim3(80, 32), 256, 0, stream>>>(Wu, 2560, 0, Wt_gu + (size_t)2560 * 1024, 1024, 2560);
  transpose_cast<<<dim3(32, 80), 256, 0, stream>>>(Wd, 1024, 0, Wt_d, 2560, 1024);

  // --- out-projection + residual (x2 -> d_out) ---
  gemm_bt<2><<<dim3(8, 64), 256, 0, stream>>>(ybf, Wt_out, x2, x, 2048, 8192, 1024);

  // --- MLP ---
  rmsnorm_kernel<<<8192, 256, 0, stream>>>(x2, n2w, h2bf, nullptr);
  gemm_bt<1><<<dim3(40, 64), 256, 0, stream>>>(h2bf, Wt_gu, gubf, nullptr, 1024, 1024, 5120);
  silu_mul_kernel<<<dim3(5, 8192), 256, 0, stream>>>(gubf, mbf);
  gemm_bt<2><<<dim3(8, 64), 256, 0, stream>>>(mbf, Wt_d, out, x2, 2560, 2560, 1024);
}

// Round 6
// 889.948 us; speedup vs baseline: 1.4358x; 1.0657x over previous
//
#include <hip/hip_runtime.h>
#include <cstdint>
#include <cmath>

// ---------------------------------------------------------------------------
// Mamba3 block forward, MI355X (gfx950).
// B=2, S=4096 (8192 tokens), D_MODEL=1024, D_INNER=2048, NHEADS=32, HD=64,
// D_STATE=64, CHUNK=64, D_MLP=2560, PROJ=9248.
// Workspace budget: ~251.5 MiB. x2 lives in d_out.
// ---------------------------------------------------------------------------

typedef __bf16 bf16;
typedef __bf16 bf16x2 __attribute__((ext_vector_type(2)));
typedef __bf16 bf16x4 __attribute__((ext_vector_type(4)));
typedef __bf16 bf16x8 __attribute__((ext_vector_type(8)));
typedef float fx4 __attribute__((ext_vector_type(4)));

#define DEV __device__ __forceinline__

// ---- workspace layout (bytes) ---------------------------------------------
// proj (bf16 8192x8192): cols z[0,2048) xg->ybf[2048,4096) B[4096,6144) C[6144,8192)
//   later: gu (8192x5120 bf16) at +0 ; m (8192x2560 bf16) at +83886080
#define OFF_PROJ    0ull
#define OFF_HHI     134217728ull   // 8192x1024 bf16 (h hi) ; later h2_bf
#define OFF_HLO     150994944ull   // 8192x1024 bf16 (h lo) ; later S (chunk sums, 512KB)
#define OFF_WTIN    167772160ull   // 8192x1024 bf16
#define OFF_WTHI    184549376ull   // 1152x1024 bf16
#define OFF_WTLO    186908672ull   // 1152x1024 bf16
#define OFF_PROJT   189267968ull   // 8192x1152 f32 (dt,theta) -- dead after rope
#define OFF_BX      189267968ull   // 4096x4096 bf16 (written at ssd1, overlays projT)
#define OFF_STATES  222822400ull   // 4096x4096 bf16 -> FS in place; dead after ssd3
#define OFF_WTOUT   222822400ull   // 1024x2048 bf16 (after ssd3, overlays states)
#define OFF_WTGU    227016704ull   // 5120x1024 bf16 (after ssd3)
#define OFF_WTD     237502464ull   // 1024x2560 bf16 (after ssd3)
#define OFF_ABUF    256376832ull   // 8192x32 f32 (per-token A)
#define OFF_XSUM    257425408ull   // 8192x32 f32
#define OFF_ROWSUM  258473984ull   // (2,64,32,64) f32
#define OFF_EXPA    260571136ull   // (2,64,32,64) f32
#define OFF_DCHUNK  262668288ull   // (2,64,32) f32
#define OFF_GAMMA   262684672ull   // 8192x32 f32
#define WS_NEEDED   263733248ull

#define OFF_GU      0ull
#define OFF_MBF     83886080ull

// ---------------------------------------------------------------------------
DEV void async_copy16(void* lds, const void* gptr) {
  __builtin_amdgcn_global_load_lds(
      (const __attribute__((address_space(1))) unsigned int*)(gptr),
      (__attribute__((address_space(3))) unsigned int*)(lds),
      16, 0, 0);
}

DEV float warp_sum64(float v) {
  #pragma unroll
  for (int o = 32; o; o >>= 1) v += __shfl_xor(v, o);
  return v;
}

DEV float red16(float v) {   // reduce across 16-lane groups (cc dimension)
  v += __shfl_xor(v, 1); v += __shfl_xor(v, 2);
  v += __shfl_xor(v, 4); v += __shfl_xor(v, 8);
  return v;
}

DEV float softplus_f(float x) { return x > 20.f ? x : log1pf(expf(x)); }
DEV float sigmoid_f(float x) { return 1.f / (1.f + expf(-x)); }

// ---------------------------------------------------------------------------
__global__ __launch_bounds__(256) void transpose_cast(
    const float* __restrict__ src, int ld, int col0,
    bf16* __restrict__ dst, int R, int C)
{
  __shared__ float tile[32][33];
  const int c0 = blockIdx.x * 32, r0 = blockIdx.y * 32;
  const int tx = threadIdx.x & 31, ty = threadIdx.x >> 5;
  #pragma unroll
  for (int ii = 0; ii < 4; ++ii) {
    int i = ty + ii * 8;
    int c = c0 + tx;
    tile[i][tx] = (c < C) ? src[(size_t)(r0 + i) * ld + col0 + c] : 0.f;
  }
  __syncthreads();
  #pragma unroll
  for (int ii = 0; ii < 4; ++ii) {
    int i = ty + ii * 8;
    dst[(size_t)(c0 + i) * R + r0 + tx] = (bf16)tile[tx][i];
  }
}

__global__ __launch_bounds__(256) void transpose_cast_hilo(
    const float* __restrict__ src, int ld, int col0,
    bf16* __restrict__ dhi, bf16* __restrict__ dlo, int R, int C)
{
  __shared__ float tile[32][33];
  const int c0 = blockIdx.x * 32, r0 = blockIdx.y * 32;
  const int tx = threadIdx.x & 31, ty = threadIdx.x >> 5;
  #pragma unroll
  for (int ii = 0; ii < 4; ++ii) {
    int i = ty + ii * 8;
    int c = c0 + tx;
    tile[i][tx] = (c < C) ? src[(size_t)(r0 + i) * ld + col0 + c] : 0.f;
  }
  __syncthreads();
  #pragma unroll
  for (int ii = 0; ii < 4; ++ii) {
    int i = ty + ii * 8;
    float v = tile[tx][i];
    bf16 hi = (bf16)v;
    size_t o = (size_t)(c0 + i) * R + r0 + tx;
    dhi[o] = hi;
    dlo[o] = (bf16)(v - (float)hi);
  }
}

// ---------------------------------------------------------------------------
__global__ __launch_bounds__(256) void rmsnorm_kernel(
    const float* __restrict__ x, const float* __restrict__ w,
    bf16* __restrict__ hi, bf16* __restrict__ lo)
{
  __shared__ float red[4];
  const size_t row = blockIdx.x;
  const int tid = threadIdx.x;
  float4 v = ((const float4*)(x + row * 1024))[tid];
  float ss = v.x * v.x + v.y * v.y + v.z * v.z + v.w * v.w;
  ss = warp_sum64(ss);
  if ((tid & 63) == 0) red[tid >> 6] = ss;
  __syncthreads();
  float tot = red[0] + red[1] + red[2] + red[3];
  float s = rsqrtf(tot * (1.f / 1024.f) + 1e-5f);
  float4 wv = ((const float4*)w)[tid];
  float h0 = v.x * s * wv.x, h1 = v.y * s * wv.y, h2 = v.z * s * wv.z, h3 = v.w * s * wv.w;
  bf16x4 hv = { (bf16)h0, (bf16)h1, (bf16)h2, (bf16)h3 };
  *(bf16x4*)(hi + row * 1024 + tid * 4) = hv;
  if (lo) {
    bf16x4 lv = { (bf16)(h0 - (float)hv[0]), (bf16)(h1 - (float)hv[1]),
                  (bf16)(h2 - (float)hv[2]), (bf16)(h3 - (float)hv[3]) };
    *(bf16x4*)(lo + row * 1024 + tid * 4) = lv;
  }
}

// ---------------------------------------------------------------------------
// Generic bf16 GEMM (m97 structure). MODE: 1=bf16 store, 2=f32 v+resid
template <int MODE>
__global__ __launch_bounds__(256) void gemm_bt(
    const bf16* A, const bf16* B, void* Cout, const float* resid,
    int K, int lda, int ldc)
{
  __shared__ bf16 As[128 * 64];
  __shared__ bf16 Bs[128 * 64];
  const int tid = threadIdx.x, wid = tid >> 6, lane = tid & 63;
  const int m0 = blockIdx.y * 128, n0 = blockIdx.x * 128;
  const int wm = (wid & 1) * 64, wn = (wid >> 1) * 64;
  fx4 acc[4][4];
  #pragma unroll
  for (int i = 0; i < 4; ++i)
    #pragma unroll
    for (int j = 0; j < 4; ++j) { fx4 z = {0.f, 0.f, 0.f, 0.f}; acc[i][j] = z; }

  const int srow = wid * 32 + (lane >> 3);
  const int slot = lane & 7;

  for (int k0 = 0; k0 < K; k0 += 64) {
    __syncthreads();
    #pragma unroll
    for (int i = 0; i < 4; ++i) {
      int m = srow + i * 8;
      int cA = ((slot ^ (m & 7)) * 8);
      async_copy16(&As[wid * 2048 + i * 512], A + (size_t)(m0 + m) * lda + k0 + cA);
    }
    #pragma unroll
    for (int i = 0; i < 4; ++i) {
      int n = srow + i * 8;
      int cB = ((slot ^ (n & 7)) * 8);
      async_copy16(&Bs[wid * 2048 + i * 512], B + (size_t)(n0 + n) * K + k0 + cB);
    }
    __syncthreads();
    #pragma unroll
    for (int kk = 0; kk < 2; ++kk) {
      bf16x8 af[4], bfr[4];
      #pragma unroll
      for (int i = 0; i < 4; ++i) {
        int mm = wm + i * 16 + (lane & 15);
        int sA = (kk * 4 + (lane >> 4)) ^ (mm & 7);
        af[i] = *(const bf16x8*)&As[mm * 64 + sA * 8];
        int nn = wn + i * 16 + (lane & 15);
        int sB = (kk * 4 + (lane >> 4)) ^ (nn & 7);
        bfr[i] = *(const bf16x8*)&Bs[nn * 64 + sB * 8];
      }
      #pragma unroll
      for (int i = 0; i < 4; ++i)
        #pragma unroll
        for (int j = 0; j < 4; ++j)
          acc[i][j] = __builtin_amdgcn_mfma_f32_16x16x32_bf16(af[i], bfr[j], acc[i][j], 0, 0, 0);
    }
  }
  const int r0 = (lane >> 4) * 4, cc = lane & 15;
  #pragma unroll
  for (int i = 0; i < 4; ++i) {
    #pragma unroll
    for (int j = 0; j < 4; ++j) {
      #pragma unroll
      for (int r = 0; r < 4; ++r) {
        int m = m0 + wm + i * 16 + r0 + r;
        int n = n0 + wn + j * 16 + cc;
        size_t off = (size_t)m * ldc + n;
        float v = acc[i][j][r];
        if (MODE == 1) ((bf16*)Cout)[off] = (bf16)v;
        else ((float*)Cout)[off] = v + resid[off];
      }
    }
  }
}

// ---------------------------------------------------------------------------
// Fused hi/lo tail GEMM: out = Ahi*Whi^T + Ahi*Wlo^T + Alo*Whi^T (f32 out).
// M=8192, N=1152, K=1024, ldc=1152. 64KB LDS (4 tiles).
__global__ __launch_bounds__(256) void gemm_tail(
    const bf16* Ahi, const bf16* Alo, const bf16* Whi, const bf16* Wlo,
    float* Cout)
{
  __shared__ bf16 Ah[128 * 64], Al[128 * 64], Bh[128 * 64], Bl[128 * 64];
  const int tid = threadIdx.x, wid = tid >> 6, lane = tid & 63;
  const int m0 = blockIdx.y * 128, n0 = blockIdx.x * 128;
  const int wm = (wid & 1) * 64, wn = (wid >> 1) * 64;
  fx4 acc[4][4];
  #pragma unroll
  for (int i = 0; i < 4; ++i)
    #pragma unroll
    for (int j = 0; j < 4; ++j) { fx4 z = {0.f, 0.f, 0.f, 0.f}; acc[i][j] = z; }

  const int srow = wid * 32 + (lane >> 3);
  const int slot = lane & 7;

  for (int k0 = 0; k0 < 1024; k0 += 64) {
    __syncthreads();
    #pragma unroll
    for (int i = 0; i < 4; ++i) {
      int m = srow + i * 8;
      int cA = ((slot ^ (m & 7)) * 8);
      size_t ao = (size_t)(m0 + m) * 1024 + k0 + cA;
      async_copy16(&Ah[wid * 2048 + i * 512], Ahi + ao);
      async_copy16(&Al[wid * 2048 + i * 512], Alo + ao);
      int n = srow + i * 8;
      int cB = ((slot ^ (n & 7)) * 8);
      size_t bo = (size_t)(n0 + n) * 1024 + k0 + cB;
      async_copy16(&Bh[wid * 2048 + i * 512], Whi + bo);
      async_copy16(&Bl[wid * 2048 + i * 512], Wlo + bo);
    }
    __syncthreads();
    #pragma unroll
    for (int kk = 0; kk < 2; ++kk) {
      bf16x8 ah[4], al[4], bh[4], bl[4];
      #pragma unroll
      for (int i = 0; i < 4; ++i) {
        int mm = wm + i * 16 + (lane & 15);
        int sA = (kk * 4 + (lane >> 4)) ^ (mm & 7);
        ah[i] = *(const bf16x8*)&Ah[mm * 64 + sA * 8];
        al[i] = *(const bf16x8*)&Al[mm * 64 + sA * 8];
        int nn = wn + i * 16 + (lane & 15);
        int sB = (kk * 4 + (lane >> 4)) ^ (nn & 7);
        bh[i] = *(const bf16x8*)&Bh[nn * 64 + sB * 8];
        bl[i] = *(const bf16x8*)&Bl[nn * 64 + sB * 8];
      }
      #pragma unroll
      for (int i = 0; i < 4; ++i)
        #pragma unroll
        for (int j = 0; j < 4; ++j) {
          acc[i][j] = __builtin_amdgcn_mfma_f32_16x16x32_bf16(ah[i], bh[j], acc[i][j], 0, 0, 0);
          acc[i][j] = __builtin_amdgcn_mfma_f32_16x16x32_bf16(ah[i], bl[j], acc[i][j], 0, 0, 0);
          acc[i][j] = __builtin_amdgcn_mfma_f32_16x16x32_bf16(al[i], bh[j], acc[i][j], 0, 0, 0);
        }
    }
  }
  const int r0 = (lane >> 4) * 4, cc = lane & 15;
  #pragma unroll
  for (int i = 0; i < 4; ++i)
    #pragma unroll
    for (int j = 0; j < 4; ++j)
      #pragma unroll
      for (int r = 0; r < 4; ++r) {
        int m = m0 + wm + i * 16 + r0 + r;
        int n = n0 + wn + j * 16 + cc;
        Cout[(size_t)m * 1152 + n] = acc[i][j][r];
      }
}

// ---------------------------------------------------------------------------
// dt/a/gamma per (token, head); dt written back into projT col h.
__global__ __launch_bounds__(256) void dt_kernel(
    float* projT, const float* __restrict__ A_log, const float* __restrict__ dt_bias,
    float* __restrict__ a_buf, float* __restrict__ gamma_buf)
{
  const int idx = blockIdx.x * 256 + threadIdx.x;   // 0..262143
  const int t = idx >> 5, h = idx & 31;
  float dtr = projT[(size_t)t * 1152 + h] + dt_bias[h];
  float dt = softplus_f(dtr);
  float a = -expf(A_log[h]) * dt;
  float alpha = expf(a);
  float gamma = (alpha - 1.f) / (a + 1e-6f) * 0.5f + 1.f;
  projT[(size_t)t * 1152 + h] = dt;
  a_buf[idx] = a;
  gamma_buf[idx] = gamma;
}

// ---------------------------------------------------------------------------
// Proj GEMM with fused per-region epilogue:
//   z[0,2048): plain bf16 store
//   x[2048,4096): xsum (row-sum over head) then *gamma
//   B[4096,6144): rmsnorm(row over head)*Bn_w + B_bias
//   C[6144,8192): rmsnorm*Cn_w + C_bias
// Each wave's 64-col footprint = exactly one head.
__global__ __launch_bounds__(256) void gemm_proj(
    const bf16* A, const bf16* B, bf16* Cout,
    const float* __restrict__ gamma_buf, float* __restrict__ xsum,
    const float* __restrict__ Bn_w, const float* __restrict__ Cn_w,
    const float* __restrict__ B_bias, const float* __restrict__ C_bias)
{
  __shared__ bf16 As[128 * 64];
  __shared__ bf16 Bs[128 * 64];
  const int tid = threadIdx.x, wid = tid >> 6, lane = tid & 63;
  const int m0 = blockIdx.y * 128, n0 = blockIdx.x * 128;
  const int wm = (wid & 1) * 64, wn = (wid >> 1) * 64;
  fx4 acc[4][4];
  #pragma unroll
  for (int i = 0; i < 4; ++i)
    #pragma unroll
    for (int j = 0; j < 4; ++j) { fx4 z = {0.f, 0.f, 0.f, 0.f}; acc[i][j] = z; }

  const int srow = wid * 32 + (lane >> 3);
  const int slot = lane & 7;

  for (int k0 = 0; k0 < 1024; k0 += 64) {
    __syncthreads();
    #pragma unroll
    for (int i = 0; i < 4; ++i) {
      int m = srow + i * 8;
      int cA = ((slot ^ (m & 7)) * 8);
      async_copy16(&As[wid * 2048 + i * 512], A + (size_t)(m0 + m) * 1024 + k0 + cA);
    }
    #pragma unroll
    for (int i = 0; i < 4; ++i) {
      int n = srow + i * 8;
      int cB = ((slot ^ (n & 7)) * 8);
      async_copy16(&Bs[wid * 2048 + i * 512], B + (size_t)(n0 + n) * 1024 + k0 + cB);
    }
    __syncthreads();
    #pragma unroll
    for (int kk = 0; kk < 2; ++kk) {
      bf16x8 af[4], bfr[4];
      #pragma unroll
      for (int i = 0; i < 4; ++i) {
        int mm = wm + i * 16 + (lane & 15);
        int sA = (kk * 4 + (lane >> 4)) ^ (mm & 7);
        af[i] = *(const bf16x8*)&As[mm * 64 + sA * 8];
        int nn = wn + i * 16 + (lane & 15);
        int sB = (kk * 4 + (lane >> 4)) ^ (nn & 7);
        bfr[i] = *(const bf16x8*)&Bs[nn * 64 + sB * 8];
      }
      #pragma unroll
      for (int i = 0; i < 4; ++i)
        #pragma unroll
        for (int j = 0; j < 4; ++j)
          acc[i][j] = __builtin_amdgcn_mfma_f32_16x16x32_bf16(af[i], bfr[j], acc[i][j], 0, 0, 0);
    }
  }
  const int r0 = (lane >> 4) * 4, cc = lane & 15;
  const int reg = n0 >> 11;                     // 0=z 1=x 2=B 3=C
  const int hh = ((n0 + wn) & 2047) >> 6;       // head for this wave
  if (reg == 0) {
    #pragma unroll
    for (int i = 0; i < 4; ++i)
      #pragma unroll
      for (int j = 0; j < 4; ++j)
        #pragma unroll
        for (int r = 0; r < 4; ++r) {
          int m = m0 + wm + i * 16 + r0 + r;
          int n = n0 + wn + j * 16 + cc;
          Cout[(size_t)m * 8192 + n] = (bf16)acc[i][j][r];
        }
  } else if (reg == 1) {
    #pragma unroll
    for (int i = 0; i < 4; ++i)
      #pragma unroll
      for (int r = 0; r < 4; ++r) {
        float s = acc[i][0][r] + acc[i][1][r] + acc[i][2][r] + acc[i][3][r];
        s = red16(s);
        int m = m0 + wm + i * 16 + r0 + r;
        if (cc == 0) xsum[(size_t)m * 32 + hh] = s;
        float g = gamma_buf[(size_t)m * 32 + hh];
        #pragma unroll
        for (int j = 0; j < 4; ++j) {
          int n = n0 + wn + j * 16 + cc;
          Cout[(size_t)m * 8192 + n] = (bf16)(acc[i][j][r] * g);
        }
      }
  } else {
    const float* w = (reg == 2) ? Bn_w : Cn_w;
    const float* bias = (reg == 2) ? B_bias : C_bias;
    float wv[4], bv[4];
    #pragma unroll
    for (int j = 0; j < 4; ++j) {
      wv[j] = w[j * 16 + cc];
      bv[j] = bias[hh * 64 + j * 16 + cc];
    }
    #pragma unroll
    for (int i = 0; i < 4; ++i)
      #pragma unroll
      for (int r = 0; r < 4; ++r) {
        float ss = acc[i][0][r] * acc[i][0][r] + acc[i][1][r] * acc[i][1][r]
                 + acc[i][2][r] * acc[i][2][r] + acc[i][3][r] * acc[i][3][r];
        ss = red16(ss);
        float sc = rsqrtf(ss * (1.f / 64.f) + 1e-5f);
        int m = m0 + wm + i * 16 + r0 + r;
        #pragma unroll
        for (int j = 0; j < 4; ++j) {
          int n = n0 + wn + j * 16 + cc;
          Cout[(size_t)m * 8192 + n] = (bf16)(acc[i][j][r] * sc * wv[j] + bv[j]);
        }
      }
  }
}

// ---------------------------------------------------------------------------
// Chunk sums of dt*theta: S[(b*64+c)][h*32+d], head-quartered grid (128,4).
__global__ __launch_bounds__(256) void chunk_sum_kernel(
    const float* __restrict__ projT, float* __restrict__ S)
{
  __shared__ float lds[8 * 288];   // 8 rows x (32 dt + 256 theta)
  const int blk = blockIdx.x;      // b*64 + c
  const int hq = blockIdx.y;       // head quarter
  const size_t row0 = (size_t)blk * 64;
  const int tid = threadIdx.x;
  float s = 0.f;
  #pragma unroll 1
  for (int batch = 0; batch < 8; ++batch) {
    __syncthreads();
    const float* src = projT + (row0 + batch * 8) * 1152;
    #pragma unroll
    for (int i = 0; i < 9; ++i) {
      int idx = i * 256 + tid;
      int r = idx / 288, col = idx - r * 288;
      int gcol = (col < 32) ? col : (32 + hq * 256 + (col - 32));
      lds[idx] = src[r * 1152 + gcol];
    }
    __syncthreads();
    int hl = tid >> 5, d = tid & 31;
    #pragma unroll
    for (int r = 0; r < 8; ++r)
      s += lds[r * 288 + hq * 8 + hl] * lds[r * 288 + 32 + hl * 32 + d];
  }
  S[(size_t)blk * 1024 + hq * 256 + tid] = s;
}

// ---------------------------------------------------------------------------
// RoPE apply, one block per (b,c,h).
__global__ __launch_bounds__(256) void rope_kernel(
    bf16* proj, const float* __restrict__ projT, const float* __restrict__ S)
{
  __shared__ float angs[64 * 33], angc[64 * 33];
  const int blk = blockIdx.x;
  const int b = blk >> 11, c = (blk >> 5) & 63, h = blk & 31;
  const size_t t0 = (size_t)b * 4096 + c * 64;
  const int w = threadIdx.x >> 6, lane = threadIdx.x & 63;
  const float* tr = projT + (t0 + lane) * 1152;
  float dtv = tr[h];
  const float* thp = tr + 32 + h * 32 + w * 8;
  float4 th0 = *(const float4*)thp;
  float4 th1 = *(const float4*)(thp + 4);
  const float* Sp = S + (size_t)(b * 64 + lane) * 1024 + h * 32 + w * 8;
  float4 S0 = *(const float4*)Sp;
  float4 S1 = *(const float4*)(Sp + 4);
  float th[8] = { th0.x, th0.y, th0.z, th0.w, th1.x, th1.y, th1.z, th1.w };
  float Sv[8] = { S0.x, S0.y, S0.z, S0.w, S1.x, S1.y, S1.z, S1.w };
  #pragma unroll 1
  for (int j = 0; j < 8; ++j) {
    int d = w * 8 + j;
    float sv = (lane < c) ? Sv[j] : 0.f;
    float off = warp_sum64(sv);
    float v = dtv * th[j];
    #pragma unroll
    for (int o = 1; o < 64; o <<= 1) { float u = __shfl_up(v, o); if (lane >= o) v += u; }
    float ang = off + v;
    float sn, cs;
    sincosf(ang, &sn, &cs);
    angs[lane * 33 + d] = sn;
    angc[lane * 33 + d] = cs;
  }
  __syncthreads();
  const int tt = threadIdx.x >> 2, q = threadIdx.x & 3;
  const size_t base = (t0 + tt) * 8192 + 4096 + h * 64 + q * 16;
  #pragma unroll
  for (int m = 0; m < 2; ++m) {   // m=0: B, m=1: C
    bf16* p = proj + base + m * 2048;
    bf16x8 v0 = *(const bf16x8*)(p);
    bf16x8 v1 = *(const bf16x8*)(p + 8);
    bf16x8 r0, r1;
    #pragma unroll
    for (int pp = 0; pp < 4; ++pp) {
      int d = q * 8 + pp;
      float e1 = (float)v0[2 * pp], e2 = (float)v0[2 * pp + 1];
      float sn = angs[tt * 33 + d], cs = angc[tt * 33 + d];
      r0[2 * pp]     = (bf16)(cs * e1 - sn * e2);
      r0[2 * pp + 1] = (bf16)(sn * e1 + cs * e2);
    }
    #pragma unroll
    for (int pp = 0; pp < 4; ++pp) {
      int d = q * 8 + 4 + pp;
      float e1 = (float)v1[2 * pp], e2 = (float)v1[2 * pp + 1];
      float sn = angs[tt * 33 + d], cs = angc[tt * 33 + d];
      r1[2 * pp]     = (bf16)(cs * e1 - sn * e2);
      r1[2 * pp + 1] = (bf16)(sn * e1 + cs * e2);
    }
    *(bf16x8*)(p) = r0;
    *(bf16x8*)(p + 8) = r1;
  }
}

// ---------------------------------------------------------------------------
// SSD stage 1 (MFMA), one block per (b,c,h) with blk = b*2048+c*32+h.
__global__ __launch_bounds__(256) void ssd1_kernel(
    const bf16* __restrict__ proj, const float* __restrict__ a_buf,
    bf16* __restrict__ Bx, bf16* __restrict__ states,
    float* __restrict__ rowsum, float* __restrict__ expac, float* __restrict__ dchunk)
{
  __shared__ bf16 Xs[64 * 72], Bs[64 * 72];
  __shared__ float acum[64], dsv[64];
  const int blk = blockIdx.x;
  const int h = blk & 31;
  const size_t bs0 = ((size_t)(blk >> 5)) * 64;
  const int tid = threadIdx.x;
  const int l = tid >> 2, p0 = (tid & 3) * 16;
  {
    const bf16* xrow = proj + (bs0 + l) * 8192 + 2048 + h * 64 + p0;
    *(bf16x8*)&Xs[l * 72 + p0]     = ((const bf16x8*)xrow)[0];
    *(bf16x8*)&Xs[l * 72 + p0 + 8] = ((const bf16x8*)xrow)[1];
    const bf16* brow = proj + (bs0 + l) * 8192 + 4096 + h * 64 + p0;
    *(bf16x8*)&Bs[l * 72 + p0]     = ((const bf16x8*)brow)[0];
    *(bf16x8*)&Bs[l * 72 + p0 + 8] = ((const bf16x8*)brow)[1];
  }
  if (tid < 64) {
    float v = a_buf[(bs0 + tid) * 32 + h];
    #pragma unroll
    for (int o = 1; o < 64; o <<= 1) { float u = __shfl_up(v, o); if (tid >= o) v += u; }
    acum[tid] = v;
    float a63 = __shfl(v, 63);
    dsv[tid] = expf(a63 - v);
    expac[(size_t)blk * 64 + tid] = expf(v);
    if (tid == 63) dchunk[blk] = expf(v);
  }
  __syncthreads();
  {
    float al = acum[l];
    float rs = 0.f;
    for (int s = tid & 3; s <= l; s += 4) rs += expf(al - acum[s]);
    rs += __shfl_xor(rs, 1);
    rs += __shfl_xor(rs, 2);
    if ((tid & 3) == 0) rowsum[(size_t)blk * 64 + l] = rs + (float)(63 - l);
  }
  const int wv = tid >> 6, lane = tid & 63;
  const int mi = lane & 15, kq = lane >> 4;
  const int m0 = wv * 16;
  fx4 accB[4], accS[4];
  #pragma unroll
  for (int j4 = 0; j4 < 4; ++j4) { fx4 z = {0.f,0.f,0.f,0.f}; accB[j4] = z; accS[j4] = z; }
  #pragma unroll
  for (int kk = 0; kk < 2; ++kk) {
    const int lb = kk * 32 + kq * 8;
    bf16x8 aX, aXd;
    #pragma unroll
    for (int j = 0; j < 8; ++j) {
      bf16 xv = Xs[(lb + j) * 72 + m0 + mi];
      aX[j] = xv;
      aXd[j] = (bf16)((float)xv * dsv[lb + j]);
    }
    #pragma unroll
    for (int j4 = 0; j4 < 4; ++j4) {
      bf16x8 bB;
      #pragma unroll
      for (int j = 0; j < 8; ++j) bB[j] = Bs[(lb + j) * 72 + j4 * 16 + mi];
      accB[j4] = __builtin_amdgcn_mfma_f32_16x16x32_bf16(aX, bB, accB[j4], 0, 0, 0);
      accS[j4] = __builtin_amdgcn_mfma_f32_16x16x32_bf16(aXd, bB, accS[j4], 0, 0, 0);
    }
  }
  const size_t obase = (size_t)blk * 4096;
  #pragma unroll
  for (int j4 = 0; j4 < 4; ++j4) {
    #pragma unroll
    for (int r = 0; r < 4; ++r) {
      int p = m0 + kq * 4 + r;
      int n = j4 * 16 + mi;
      Bx[obase + p * 64 + n] = (bf16)accB[j4][r];
      states[obase + p * 64 + n] = (bf16)accS[j4][r];
    }
  }
}

// ---------------------------------------------------------------------------
// SSD stage 2: inclusive scan over chunks (f32 carry, bf16 storage).
__global__ __launch_bounds__(128) void ssd2_kernel(
    bf16* __restrict__ states, const float* __restrict__ dchunk)
{
  const int blk = blockIdx.x;  // 1024 = b(2) x h(32) x q(16)
  const int b = blk >> 9, rest = blk & 511;
  const int h = rest >> 4, q = rest & 15;
  const int e0 = q * 256 + threadIdx.x * 2;
  float fs0 = 0.f, fs1 = 0.f;
  #pragma unroll 2
  for (int c = 0; c < 64; ++c) {
    size_t idx = ((size_t)(b * 2048 + c * 32 + h) * 4096) + e0;
    float dec = dchunk[b * 2048 + c * 32 + h];
    bf16x2 st = *(const bf16x2*)(states + idx);
    fs0 = fs0 * dec + (float)st[0];
    fs1 = fs1 * dec + (float)st[1];
    bf16x2 o = { (bf16)fs0, (bf16)fs1 };
    *(bf16x2*)(states + idx) = o;
  }
}

// ---------------------------------------------------------------------------
// SSD stage 3 (MFMA), one block per (b,c,h).
__global__ __launch_bounds__(256) void ssd3_kernel(
    bf16* proj, const bf16* __restrict__ Bx, const bf16* __restrict__ FS,
    const float* __restrict__ rowsum, const float* __restrict__ expac,
    const float* __restrict__ xsum, const float* __restrict__ D_param)
{
  __shared__ bf16 Cs[64 * 72], BxS[64 * 72], FSs[64 * 72];
  __shared__ float rs_s[64], ea_s[64], sk_s[64];
  const int blk = blockIdx.x;
  const int h = blk & 31;
  const size_t bs0 = ((size_t)(blk >> 5)) * 64;
  const int tid = threadIdx.x;
  const int l = tid >> 2, q0 = (tid & 3) * 16;
  {
    const bf16* crow = proj + (bs0 + l) * 8192 + 6144 + h * 64 + q0;
    *(bf16x8*)&Cs[l * 72 + q0]     = ((const bf16x8*)crow)[0];
    *(bf16x8*)&Cs[l * 72 + q0 + 8] = ((const bf16x8*)crow)[1];
    size_t mb = (size_t)blk * 4096 + l * 64 + q0;
    *(bf16x8*)&BxS[l * 72 + q0]     = ((const bf16x8*)(Bx + mb))[0];
    *(bf16x8*)&BxS[l * 72 + q0 + 8] = ((const bf16x8*)(Bx + mb))[1];
    *(bf16x8*)&FSs[l * 72 + q0]     = ((const bf16x8*)(FS + mb))[0];
    *(bf16x8*)&FSs[l * 72 + q0 + 8] = ((const bf16x8*)(FS + mb))[1];
  }
  if (tid < 64) {
    rs_s[tid] = rowsum[(size_t)blk * 64 + tid];
    ea_s[tid] = expac[(size_t)blk * 64 + tid];
    sk_s[tid] = D_param[h] * xsum[(bs0 + tid) * 32 + h];
  }
  __syncthreads();
  const int wv = tid >> 6, lane = tid & 63;
  const int mi = lane & 15, kq = lane >> 4;
  const int m0 = wv * 16;
  fx4 acc1[4], acc2[4];
  #pragma unroll
  for (int j4 = 0; j4 < 4; ++j4) { fx4 z = {0.f,0.f,0.f,0.f}; acc1[j4] = z; acc2[j4] = z; }
  #pragma unroll
  for (int kk = 0; kk < 2; ++kk) {
    bf16x8 aC = *(const bf16x8*)&Cs[(m0 + mi) * 72 + kk * 32 + kq * 8];
    #pragma unroll
    for (int j4 = 0; j4 < 4; ++j4) {
      bf16x8 bx = *(const bf16x8*)&BxS[(j4 * 16 + mi) * 72 + kk * 32 + kq * 8];
      bf16x8 fs = *(const bf16x8*)&FSs[(j4 * 16 + mi) * 72 + kk * 32 + kq * 8];
      acc1[j4] = __builtin_amdgcn_mfma_f32_16x16x32_bf16(aC, bx, acc1[j4], 0, 0, 0);
      acc2[j4] = __builtin_amdgcn_mfma_f32_16x16x32_bf16(aC, fs, acc2[j4], 0, 0, 0);
    }
  }
  #pragma unroll
  for (int j4 = 0; j4 < 4; ++j4) {
    #pragma unroll
    for (int r = 0; r < 4; ++r) {
      int li = m0 + kq * 4 + r;
      int p = j4 * 16 + mi;
      float y = rs_s[li] * acc1[j4][r] + ea_s[li] * acc2[j4][r] + sk_s[li];
      size_t zoff = (bs0 + li) * 8192 + h * 64 + p;
      float z = (float)proj[zoff];
      proj[zoff + 2048] = (bf16)(y * z * sigmoid_f(z));
    }
  }
}

// ---------------------------------------------------------------------------
__global__ __launch_bounds__(256) void silu_mul_kernel(
    const bf16* __restrict__ gu, bf16* __restrict__ m)
{
  const size_t row = blockIdx.y;
  const int col2 = blockIdx.x * 256 + threadIdx.x;  // 0..1279
  const size_t gi = row * 5120 + col2 * 2;
  bf16x2 g = *(const bf16x2*)(gu + gi);
  bf16x2 u = *(const bf16x2*)(gu + gi + 2560);
  float g0 = (float)g[0], g1 = (float)g[1];
  float m0 = g0 * sigmoid_f(g0) * (float)u[0];
  float m1 = g1 * sigmoid_f(g1) * (float)u[1];
  bf16x2 mv = { (bf16)m0, (bf16)m1 };
  *(bf16x2*)(m + row * 2560 + col2 * 2) = mv;
}

// ---------------------------------------------------------------------------
extern "C" void kernel_launch(void* const* d_in, const int* in_sizes, int n_in,
                              void* d_out, int out_size, void* d_ws, size_t ws_size,
                              hipStream_t stream) {
  (void)in_sizes; (void)n_in; (void)out_size;
  if (ws_size < WS_NEEDED) return;  // diagnostic guard: fail absmax, not SIGABRT
  const float* x       = (const float*)d_in[0];
  const float* n1w     = (const float*)d_in[1];
  const float* n2w     = (const float*)d_in[2];
  const float* W_in    = (const float*)d_in[3];
  const float* W_out   = (const float*)d_in[4];
  const float* A_log   = (const float*)d_in[5];
  const float* D_param = (const float*)d_in[6];
  const float* dt_bias = (const float*)d_in[7];
  const float* B_bias  = (const float*)d_in[8];
  const float* C_bias  = (const float*)d_in[9];
  const float* Bn_w    = (const float*)d_in[10];
  const float* Cn_w    = (const float*)d_in[11];
  const float* Wg      = (const float*)d_in[12];
  const float* Wu      = (const float*)d_in[13];
  const float* Wd      = (const float*)d_in[14];
  float* out = (float*)d_out;
  char* ws = (char*)d_ws;

  bf16*  proj   = (bf16*)(ws + OFF_PROJ);
  float* projT  = (float*)(ws + OFF_PROJT);
  bf16*  h_hi   = (bf16*)(ws + OFF_HHI);
  bf16*  h_lo   = (bf16*)(ws + OFF_HLO);
  bf16*  Wt_in  = (bf16*)(ws + OFF_WTIN);
  bf16*  Wt_hi  = (bf16*)(ws + OFF_WTHI);
  bf16*  Wt_lo  = (bf16*)(ws + OFF_WTLO);
  bf16*  Wt_out = (bf16*)(ws + OFF_WTOUT);
  bf16*  Wt_gu  = (bf16*)(ws + OFF_WTGU);
  bf16*  Wt_d   = (bf16*)(ws + OFF_WTD);
  bf16*  Bx     = (bf16*)(ws + OFF_BX);
  bf16*  states = (bf16*)(ws + OFF_STATES);
  float* a_buf  = (float*)(ws + OFF_ABUF);
  float* xsum_  = (float*)(ws + OFF_XSUM);
  float* rowsum = (float*)(ws + OFF_ROWSUM);
  float* expac  = (float*)(ws + OFF_EXPA);
  float* dchunk = (float*)(ws + OFF_DCHUNK);
  float* gamma_ = (float*)(ws + OFF_GAMMA);
  float* Ssum   = (float*)(ws + OFF_HLO);    // 512KB chunk sums (h_lo dead by then)
  bf16*  ybf    = proj + 2048;               // cols [2048,4096) of proj, lda 8192
  bf16*  gubf   = (bf16*)(ws + OFF_GU);
  bf16*  mbf    = (bf16*)(ws + OFF_MBF);
  bf16*  h2bf   = h_hi;                      // reuse after proj GEMMs
  float* x2     = out;                       // x2 lives in d_out

  // --- weight transposes needed up-front ---
  transpose_cast<<<dim3(256, 32), 256, 0, stream>>>(W_in, 9248, 0, Wt_in, 1024, 8192);
  transpose_cast_hilo<<<dim3(36, 32), 256, 0, stream>>>(W_in, 9248, 8192, Wt_hi, Wt_lo, 1024, 1056);

  // --- norm1 (hi/lo split for the precision-critical dt/theta tail GEMM) ---
  rmsnorm_kernel<<<8192, 256, 0, stream>>>(x, n1w, h_hi, h_lo);

  // --- in-projection: fused hi/lo tail, then dt, then proj w/ fused prep ---
  gemm_tail<<<dim3(9, 64), 256, 0, stream>>>(h_hi, h_lo, Wt_hi, Wt_lo, projT);
  dt_kernel<<<1024, 256, 0, stream>>>(projT, A_log, dt_bias, a_buf, gamma_);
  gemm_proj<<<dim3(64, 64), 256, 0, stream>>>(h_hi, Wt_in, proj, gamma_, xsum_,
                                              Bn_w, Cn_w, B_bias, C_bias);

  // --- hierarchical RoPE ---
  chunk_sum_kernel<<<dim3(128, 4), 256, 0, stream>>>(projT, Ssum);
  rope_kernel<<<4096, 256, 0, stream>>>(proj, projT, Ssum);

  // --- SSD (MFMA) ---
  ssd1_kernel<<<4096, 256, 0, stream>>>(proj, a_buf, Bx, states, rowsum, expac, dchunk);
  ssd2_kernel<<<1024, 128, 0, stream>>>(states, dchunk);
  ssd3_kernel<<<4096, 256, 0, stream>>>(proj, Bx, states, rowsum, expac, xsum_, D_param);

  // --- late weight transposes (overlay dead states region) ---
  transpose_cast<<<dim3(32, 64), 256, 0, stream>>>(W_out, 1024, 0, Wt_out, 2048, 1024);
  transpose_cast<<<dim3(80, 32), 256, 0, stream>>>(Wg, 2560, 0, Wt_gu, 1024, 2560);
  transpose_cast<<<dim3(80, 32), 256, 0, stream>>>(Wu, 2560, 0, Wt_gu + (size_t)2560 * 1024, 1024, 2560);
  transpose_cast<<<dim3(32, 80), 256, 0, stream>>>(Wd, 1024, 0, Wt_d, 2560, 1024);

  // --- out-projection + residual (x2 -> d_out) ---
  gemm_bt<2><<<dim3(8, 64), 256, 0, stream>>>(ybf, Wt_out, x2, x, 2048, 8192, 1024);

  // --- MLP ---
  rmsnorm_kernel<<<8192, 256, 0, stream>>>(x2, n2w, h2bf, nullptr);
  gemm_bt<1><<<dim3(40, 64), 256, 0, stream>>>(h2bf, Wt_gu, gubf, nullptr, 1024, 1024, 5120);
  silu_mul_kernel<<<dim3(5, 8192), 256, 0, stream>>>(gubf, mbf);
  gemm_bt<2><<<dim3(8, 64), 256, 0, stream>>>(mbf, Wt_d, out, x2, 2560, 2560, 1024);
}

// Round 7
// 841.362 us; speedup vs baseline: 1.5187x; 1.0577x over previous
//
#include <hip/hip_runtime.h>
#include <cstdint>
#include <cmath>

// ---------------------------------------------------------------------------
// Mamba3 block forward, MI355X (gfx950).
// B=2, S=4096 (8192 tokens), D_MODEL=1024, D_INNER=2048, NHEADS=32, HD=64,
// D_STATE=64, CHUNK=64, D_MLP=2560, PROJ=9248.
// Workspace budget: ~251.5 MiB. x2 lives in d_out.
// ---------------------------------------------------------------------------

typedef __bf16 bf16;
typedef __bf16 bf16x2 __attribute__((ext_vector_type(2)));
typedef __bf16 bf16x4 __attribute__((ext_vector_type(4)));
typedef __bf16 bf16x8 __attribute__((ext_vector_type(8)));
typedef float fx4 __attribute__((ext_vector_type(4)));

#define DEV __device__ __forceinline__

// ---- workspace layout (bytes) ---------------------------------------------
// proj (bf16 8192x8192): cols z[0,2048) xg->ybf[2048,4096) B[4096,6144) C[6144,8192)
//   later: gu (8192x5120 bf16) at +0 ; m (8192x2560 bf16) at +83886080
#define OFF_PROJ    0ull
#define OFF_HHI     134217728ull   // 8192x1024 bf16 (h hi) ; later h2_bf
#define OFF_HLO     150994944ull   // 8192x1024 bf16 (h lo) ; later S (chunk sums, 512KB)
#define OFF_WTIN    167772160ull   // 8192x1024 bf16
#define OFF_WTHI    184549376ull   // 1152x1024 bf16
#define OFF_WTLO    186908672ull   // 1152x1024 bf16
#define OFF_PROJT   189267968ull   // 8192x1152 f32 (dt,theta) -- dead after rope
#define OFF_BX      189267968ull   // 4096x4096 bf16 (written at ssd1, overlays projT)
#define OFF_STATES  222822400ull   // 4096x4096 bf16 -> FS in place; dead after ssd3
#define OFF_WTOUT   222822400ull   // 1024x2048 bf16 (after ssd3, overlays states)
#define OFF_WTGU    227016704ull   // 5120x1024 bf16 (after ssd3)
#define OFF_WTD     237502464ull   // 1024x2560 bf16 (after ssd3)
#define OFF_ABUF    256376832ull   // 8192x32 f32 (per-token A)
#define OFF_XSUM    257425408ull   // 8192x32 f32
#define OFF_ROWSUM  258473984ull   // (2,64,32,64) f32
#define OFF_EXPA    260571136ull   // (2,64,32,64) f32
#define OFF_DCHUNK  262668288ull   // (2,64,32) f32
#define OFF_GAMMA   262684672ull   // 8192x32 f32
#define WS_NEEDED   263733248ull

#define OFF_GU      0ull
#define OFF_MBF     83886080ull

// ---------------------------------------------------------------------------
DEV void async_copy16(void* lds, const void* gptr) {
  __builtin_amdgcn_global_load_lds(
      (const __attribute__((address_space(1))) unsigned int*)(gptr),
      (__attribute__((address_space(3))) unsigned int*)(lds),
      16, 0, 0);
}

DEV float warp_sum64(float v) {
  #pragma unroll
  for (int o = 32; o; o >>= 1) v += __shfl_xor(v, o);
  return v;
}

DEV float red16(float v) {   // reduce across 16-lane groups (cc dimension)
  v += __shfl_xor(v, 1); v += __shfl_xor(v, 2);
  v += __shfl_xor(v, 4); v += __shfl_xor(v, 8);
  return v;
}

DEV float softplus_f(float x) { return x > 20.f ? x : log1pf(expf(x)); }
DEV float sigmoid_f(float x) { return 1.f / (1.f + expf(-x)); }

// ---------------------------------------------------------------------------
__global__ __launch_bounds__(256) void transpose_cast(
    const float* __restrict__ src, int ld, int col0,
    bf16* __restrict__ dst, int R, int C)
{
  __shared__ float tile[32][33];
  const int c0 = blockIdx.x * 32, r0 = blockIdx.y * 32;
  const int tx = threadIdx.x & 31, ty = threadIdx.x >> 5;
  #pragma unroll
  for (int ii = 0; ii < 4; ++ii) {
    int i = ty + ii * 8;
    int c = c0 + tx;
    tile[i][tx] = (c < C) ? src[(size_t)(r0 + i) * ld + col0 + c] : 0.f;
  }
  __syncthreads();
  #pragma unroll
  for (int ii = 0; ii < 4; ++ii) {
    int i = ty + ii * 8;
    dst[(size_t)(c0 + i) * R + r0 + tx] = (bf16)tile[tx][i];
  }
}

__global__ __launch_bounds__(256) void transpose_cast_hilo(
    const float* __restrict__ src, int ld, int col0,
    bf16* __restrict__ dhi, bf16* __restrict__ dlo, int R, int C)
{
  __shared__ float tile[32][33];
  const int c0 = blockIdx.x * 32, r0 = blockIdx.y * 32;
  const int tx = threadIdx.x & 31, ty = threadIdx.x >> 5;
  #pragma unroll
  for (int ii = 0; ii < 4; ++ii) {
    int i = ty + ii * 8;
    int c = c0 + tx;
    tile[i][tx] = (c < C) ? src[(size_t)(r0 + i) * ld + col0 + c] : 0.f;
  }
  __syncthreads();
  #pragma unroll
  for (int ii = 0; ii < 4; ++ii) {
    int i = ty + ii * 8;
    float v = tile[tx][i];
    bf16 hi = (bf16)v;
    size_t o = (size_t)(c0 + i) * R + r0 + tx;
    dhi[o] = hi;
    dlo[o] = (bf16)(v - (float)hi);
  }
}

// ---------------------------------------------------------------------------
__global__ __launch_bounds__(256) void rmsnorm_kernel(
    const float* __restrict__ x, const float* __restrict__ w,
    bf16* __restrict__ hi, bf16* __restrict__ lo)
{
  __shared__ float red[4];
  const size_t row = blockIdx.x;
  const int tid = threadIdx.x;
  float4 v = ((const float4*)(x + row * 1024))[tid];
  float ss = v.x * v.x + v.y * v.y + v.z * v.z + v.w * v.w;
  ss = warp_sum64(ss);
  if ((tid & 63) == 0) red[tid >> 6] = ss;
  __syncthreads();
  float tot = red[0] + red[1] + red[2] + red[3];
  float s = rsqrtf(tot * (1.f / 1024.f) + 1e-5f);
  float4 wv = ((const float4*)w)[tid];
  float h0 = v.x * s * wv.x, h1 = v.y * s * wv.y, h2 = v.z * s * wv.z, h3 = v.w * s * wv.w;
  bf16x4 hv = { (bf16)h0, (bf16)h1, (bf16)h2, (bf16)h3 };
  *(bf16x4*)(hi + row * 1024 + tid * 4) = hv;
  if (lo) {
    bf16x4 lv = { (bf16)(h0 - (float)hv[0]), (bf16)(h1 - (float)hv[1]),
                  (bf16)(h2 - (float)hv[2]), (bf16)(h3 - (float)hv[3]) };
    *(bf16x4*)(lo + row * 1024 + tid * 4) = lv;
  }
}

// ---------------------------------------------------------------------------
// Generic bf16 GEMM (m97 structure). MODE: 1=bf16 store, 2=f32 v+resid
template <int MODE>
__global__ __launch_bounds__(256) void gemm_bt(
    const bf16* A, const bf16* B, void* Cout, const float* resid,
    int K, int lda, int ldc)
{
  __shared__ bf16 As[128 * 64];
  __shared__ bf16 Bs[128 * 64];
  const int tid = threadIdx.x, wid = tid >> 6, lane = tid & 63;
  const int m0 = blockIdx.y * 128, n0 = blockIdx.x * 128;
  const int wm = (wid & 1) * 64, wn = (wid >> 1) * 64;
  fx4 acc[4][4];
  #pragma unroll
  for (int i = 0; i < 4; ++i)
    #pragma unroll
    for (int j = 0; j < 4; ++j) { fx4 z = {0.f, 0.f, 0.f, 0.f}; acc[i][j] = z; }

  const int srow = wid * 32 + (lane >> 3);
  const int slot = lane & 7;

  for (int k0 = 0; k0 < K; k0 += 64) {
    __syncthreads();
    #pragma unroll
    for (int i = 0; i < 4; ++i) {
      int m = srow + i * 8;
      int cA = ((slot ^ (m & 7)) * 8);
      async_copy16(&As[wid * 2048 + i * 512], A + (size_t)(m0 + m) * lda + k0 + cA);
    }
    #pragma unroll
    for (int i = 0; i < 4; ++i) {
      int n = srow + i * 8;
      int cB = ((slot ^ (n & 7)) * 8);
      async_copy16(&Bs[wid * 2048 + i * 512], B + (size_t)(n0 + n) * K + k0 + cB);
    }
    __syncthreads();
    #pragma unroll
    for (int kk = 0; kk < 2; ++kk) {
      bf16x8 af[4], bfr[4];
      #pragma unroll
      for (int i = 0; i < 4; ++i) {
        int mm = wm + i * 16 + (lane & 15);
        int sA = (kk * 4 + (lane >> 4)) ^ (mm & 7);
        af[i] = *(const bf16x8*)&As[mm * 64 + sA * 8];
        int nn = wn + i * 16 + (lane & 15);
        int sB = (kk * 4 + (lane >> 4)) ^ (nn & 7);
        bfr[i] = *(const bf16x8*)&Bs[nn * 64 + sB * 8];
      }
      #pragma unroll
      for (int i = 0; i < 4; ++i)
        #pragma unroll
        for (int j = 0; j < 4; ++j)
          acc[i][j] = __builtin_amdgcn_mfma_f32_16x16x32_bf16(af[i], bfr[j], acc[i][j], 0, 0, 0);
    }
  }
  const int r0 = (lane >> 4) * 4, cc = lane & 15;
  #pragma unroll
  for (int i = 0; i < 4; ++i) {
    #pragma unroll
    for (int j = 0; j < 4; ++j) {
      #pragma unroll
      for (int r = 0; r < 4; ++r) {
        int m = m0 + wm + i * 16 + r0 + r;
        int n = n0 + wn + j * 16 + cc;
        size_t off = (size_t)m * ldc + n;
        float v = acc[i][j][r];
        if (MODE == 1) ((bf16*)Cout)[off] = (bf16)v;
        else ((float*)Cout)[off] = v + resid[off];
      }
    }
  }
}

// ---------------------------------------------------------------------------
// Fused hi/lo tail GEMM: out = Ahi*Whi^T + Ahi*Wlo^T + Alo*Whi^T (f32 out).
// M=8192, N=1152, K=1024, ldc=1152. 64KB LDS (4 tiles).
__global__ __launch_bounds__(256) void gemm_tail(
    const bf16* Ahi, const bf16* Alo, const bf16* Whi, const bf16* Wlo,
    float* Cout)
{
  __shared__ bf16 Ah[128 * 64], Al[128 * 64], Bh[128 * 64], Bl[128 * 64];
  const int tid = threadIdx.x, wid = tid >> 6, lane = tid & 63;
  const int m0 = blockIdx.y * 128, n0 = blockIdx.x * 128;
  const int wm = (wid & 1) * 64, wn = (wid >> 1) * 64;
  fx4 acc[4][4];
  #pragma unroll
  for (int i = 0; i < 4; ++i)
    #pragma unroll
    for (int j = 0; j < 4; ++j) { fx4 z = {0.f, 0.f, 0.f, 0.f}; acc[i][j] = z; }

  const int srow = wid * 32 + (lane >> 3);
  const int slot = lane & 7;

  for (int k0 = 0; k0 < 1024; k0 += 64) {
    __syncthreads();
    #pragma unroll
    for (int i = 0; i < 4; ++i) {
      int m = srow + i * 8;
      int cA = ((slot ^ (m & 7)) * 8);
      size_t ao = (size_t)(m0 + m) * 1024 + k0 + cA;
      async_copy16(&Ah[wid * 2048 + i * 512], Ahi + ao);
      async_copy16(&Al[wid * 2048 + i * 512], Alo + ao);
      int n = srow + i * 8;
      int cB = ((slot ^ (n & 7)) * 8);
      size_t bo = (size_t)(n0 + n) * 1024 + k0 + cB;
      async_copy16(&Bh[wid * 2048 + i * 512], Whi + bo);
      async_copy16(&Bl[wid * 2048 + i * 512], Wlo + bo);
    }
    __syncthreads();
    #pragma unroll
    for (int kk = 0; kk < 2; ++kk) {
      bf16x8 ah[4], al[4], bh[4], bl[4];
      #pragma unroll
      for (int i = 0; i < 4; ++i) {
        int mm = wm + i * 16 + (lane & 15);
        int sA = (kk * 4 + (lane >> 4)) ^ (mm & 7);
        ah[i] = *(const bf16x8*)&Ah[mm * 64 + sA * 8];
        al[i] = *(const bf16x8*)&Al[mm * 64 + sA * 8];
        int nn = wn + i * 16 + (lane & 15);
        int sB = (kk * 4 + (lane >> 4)) ^ (nn & 7);
        bh[i] = *(const bf16x8*)&Bh[nn * 64 + sB * 8];
        bl[i] = *(const bf16x8*)&Bl[nn * 64 + sB * 8];
      }
      #pragma unroll
      for (int i = 0; i < 4; ++i)
        #pragma unroll
        for (int j = 0; j < 4; ++j) {
          acc[i][j] = __builtin_amdgcn_mfma_f32_16x16x32_bf16(ah[i], bh[j], acc[i][j], 0, 0, 0);
          acc[i][j] = __builtin_amdgcn_mfma_f32_16x16x32_bf16(ah[i], bl[j], acc[i][j], 0, 0, 0);
          acc[i][j] = __builtin_amdgcn_mfma_f32_16x16x32_bf16(al[i], bh[j], acc[i][j], 0, 0, 0);
        }
    }
  }
  const int r0 = (lane >> 4) * 4, cc = lane & 15;
  #pragma unroll
  for (int i = 0; i < 4; ++i)
    #pragma unroll
    for (int j = 0; j < 4; ++j)
      #pragma unroll
      for (int r = 0; r < 4; ++r) {
        int m = m0 + wm + i * 16 + r0 + r;
        int n = n0 + wn + j * 16 + cc;
        Cout[(size_t)m * 1152 + n] = acc[i][j][r];
      }
}

// ---------------------------------------------------------------------------
// dt/a/gamma per (token, head); dt written back into projT col h.
__global__ __launch_bounds__(256) void dt_kernel(
    float* projT, const float* __restrict__ A_log, const float* __restrict__ dt_bias,
    float* __restrict__ a_buf, float* __restrict__ gamma_buf)
{
  const int idx = blockIdx.x * 256 + threadIdx.x;   // 0..262143
  const int t = idx >> 5, h = idx & 31;
  float dtr = projT[(size_t)t * 1152 + h] + dt_bias[h];
  float dt = softplus_f(dtr);
  float a = -expf(A_log[h]) * dt;
  float alpha = expf(a);
  float gamma = (alpha - 1.f) / (a + 1e-6f) * 0.5f + 1.f;
  projT[(size_t)t * 1152 + h] = dt;
  a_buf[idx] = a;
  gamma_buf[idx] = gamma;
}

// ---------------------------------------------------------------------------
// Proj GEMM with fused per-region epilogue. __launch_bounds__(256,6) caps
// VGPR at ~85 so the K-loop keeps 6 waves/SIMD (the r5 regression was the
// 104-VGPR occupancy cliff: MfmaUtil 41->29). Epilogue spills are free.
//   z[0,2048): plain bf16 store
//   x[2048,4096): xsum (row-sum over head) then *gamma
//   B[4096,6144): rmsnorm(row)*Bn_w + B_bias ; C[6144,8192): same w/ Cn_w
__global__ __launch_bounds__(256, 6) void gemm_proj(
    const bf16* A, const bf16* B, bf16* Cout,
    const float* __restrict__ gamma_buf, float* __restrict__ xsum,
    const float* __restrict__ Bn_w, const float* __restrict__ Cn_w,
    const float* __restrict__ B_bias, const float* __restrict__ C_bias)
{
  __shared__ bf16 As[128 * 64];
  __shared__ bf16 Bs[128 * 64];
  const int tid = threadIdx.x, wid = tid >> 6, lane = tid & 63;
  const int m0 = blockIdx.y * 128, n0 = blockIdx.x * 128;
  const int wm = (wid & 1) * 64, wn = (wid >> 1) * 64;
  fx4 acc[4][4];
  #pragma unroll
  for (int i = 0; i < 4; ++i)
    #pragma unroll
    for (int j = 0; j < 4; ++j) { fx4 z = {0.f, 0.f, 0.f, 0.f}; acc[i][j] = z; }

  const int srow = wid * 32 + (lane >> 3);
  const int slot = lane & 7;

  for (int k0 = 0; k0 < 1024; k0 += 64) {
    __syncthreads();
    #pragma unroll
    for (int i = 0; i < 4; ++i) {
      int m = srow + i * 8;
      int cA = ((slot ^ (m & 7)) * 8);
      async_copy16(&As[wid * 2048 + i * 512], A + (size_t)(m0 + m) * 1024 + k0 + cA);
    }
    #pragma unroll
    for (int i = 0; i < 4; ++i) {
      int n = srow + i * 8;
      int cB = ((slot ^ (n & 7)) * 8);
      async_copy16(&Bs[wid * 2048 + i * 512], B + (size_t)(n0 + n) * 1024 + k0 + cB);
    }
    __syncthreads();
    #pragma unroll
    for (int kk = 0; kk < 2; ++kk) {
      bf16x8 af[4], bfr[4];
      #pragma unroll
      for (int i = 0; i < 4; ++i) {
        int mm = wm + i * 16 + (lane & 15);
        int sA = (kk * 4 + (lane >> 4)) ^ (mm & 7);
        af[i] = *(const bf16x8*)&As[mm * 64 + sA * 8];
        int nn = wn + i * 16 + (lane & 15);
        int sB = (kk * 4 + (lane >> 4)) ^ (nn & 7);
        bfr[i] = *(const bf16x8*)&Bs[nn * 64 + sB * 8];
      }
      #pragma unroll
      for (int i = 0; i < 4; ++i)
        #pragma unroll
        for (int j = 0; j < 4; ++j)
          acc[i][j] = __builtin_amdgcn_mfma_f32_16x16x32_bf16(af[i], bfr[j], acc[i][j], 0, 0, 0);
    }
  }
  const int r0 = (lane >> 4) * 4, cc = lane & 15;
  const int reg = n0 >> 11;                     // 0=z 1=x 2=B 3=C
  const int hh = ((n0 + wn) & 2047) >> 6;       // head for this wave
  if (reg == 0) {
    #pragma unroll
    for (int i = 0; i < 4; ++i)
      #pragma unroll
      for (int j = 0; j < 4; ++j)
        #pragma unroll
        for (int r = 0; r < 4; ++r) {
          int m = m0 + wm + i * 16 + r0 + r;
          int n = n0 + wn + j * 16 + cc;
          Cout[(size_t)m * 8192 + n] = (bf16)acc[i][j][r];
        }
  } else if (reg == 1) {
    #pragma unroll
    for (int i = 0; i < 4; ++i)
      #pragma unroll
      for (int r = 0; r < 4; ++r) {
        float s = acc[i][0][r] + acc[i][1][r] + acc[i][2][r] + acc[i][3][r];
        s = red16(s);
        int m = m0 + wm + i * 16 + r0 + r;
        if (cc == 0) xsum[(size_t)m * 32 + hh] = s;
        float g = gamma_buf[(size_t)m * 32 + hh];
        #pragma unroll
        for (int j = 0; j < 4; ++j) {
          int n = n0 + wn + j * 16 + cc;
          Cout[(size_t)m * 8192 + n] = (bf16)(acc[i][j][r] * g);
        }
      }
  } else {
    const float* w = (reg == 2) ? Bn_w : Cn_w;
    const float* bias = (reg == 2) ? B_bias : C_bias;
    #pragma unroll
    for (int i = 0; i < 4; ++i)
      #pragma unroll
      for (int r = 0; r < 4; ++r) {
        float ss = acc[i][0][r] * acc[i][0][r] + acc[i][1][r] * acc[i][1][r]
                 + acc[i][2][r] * acc[i][2][r] + acc[i][3][r] * acc[i][3][r];
        ss = red16(ss);
        float sc = rsqrtf(ss * (1.f / 64.f) + 1e-5f);
        int m = m0 + wm + i * 16 + r0 + r;
        #pragma unroll
        for (int j = 0; j < 4; ++j) {
          int n = n0 + wn + j * 16 + cc;
          Cout[(size_t)m * 8192 + n] =
              (bf16)(acc[i][j][r] * sc * w[j * 16 + cc] + bias[hh * 64 + j * 16 + cc]);
        }
      }
  }
}

// ---------------------------------------------------------------------------
// Chunk sums of dt*theta: S[(b*64+c)][h*32+d], head-quartered grid (128,4).
__global__ __launch_bounds__(256) void chunk_sum_kernel(
    const float* __restrict__ projT, float* __restrict__ S)
{
  __shared__ float lds[8 * 288];   // 8 rows x (32 dt + 256 theta)
  const int blk = blockIdx.x;      // b*64 + c
  const int hq = blockIdx.y;       // head quarter
  const size_t row0 = (size_t)blk * 64;
  const int tid = threadIdx.x;
  float s = 0.f;
  #pragma unroll 1
  for (int batch = 0; batch < 8; ++batch) {
    __syncthreads();
    const float* src = projT + (row0 + batch * 8) * 1152;
    #pragma unroll
    for (int i = 0; i < 9; ++i) {
      int idx = i * 256 + tid;
      int r = idx / 288, col = idx - r * 288;
      int gcol = (col < 32) ? col : (32 + hq * 256 + (col - 32));
      lds[idx] = src[r * 1152 + gcol];
    }
    __syncthreads();
    int hl = tid >> 5, d = tid & 31;
    #pragma unroll
    for (int r = 0; r < 8; ++r)
      s += lds[r * 288 + hq * 8 + hl] * lds[r * 288 + 32 + hl * 32 + d];
  }
  S[(size_t)blk * 1024 + hq * 256 + tid] = s;
}

// ---------------------------------------------------------------------------
// RoPE apply, one block per (b,c,h).
__global__ __launch_bounds__(256) void rope_kernel(
    bf16* proj, const float* __restrict__ projT, const float* __restrict__ S)
{
  __shared__ float angs[64 * 33], angc[64 * 33];
  const int blk = blockIdx.x;
  const int b = blk >> 11, c = (blk >> 5) & 63, h = blk & 31;
  const size_t t0 = (size_t)b * 4096 + c * 64;
  const int w = threadIdx.x >> 6, lane = threadIdx.x & 63;
  const float* tr = projT + (t0 + lane) * 1152;
  float dtv = tr[h];
  const float* thp = tr + 32 + h * 32 + w * 8;
  float4 th0 = *(const float4*)thp;
  float4 th1 = *(const float4*)(thp + 4);
  const float* Sp = S + (size_t)(b * 64 + lane) * 1024 + h * 32 + w * 8;
  float4 S0 = *(const float4*)Sp;
  float4 S1 = *(const float4*)(Sp + 4);
  float th[8] = { th0.x, th0.y, th0.z, th0.w, th1.x, th1.y, th1.z, th1.w };
  float Sv[8] = { S0.x, S0.y, S0.z, S0.w, S1.x, S1.y, S1.z, S1.w };
  #pragma unroll 1
  for (int j = 0; j < 8; ++j) {
    int d = w * 8 + j;
    float sv = (lane < c) ? Sv[j] : 0.f;
    float off = warp_sum64(sv);
    float v = dtv * th[j];
    #pragma unroll
    for (int o = 1; o < 64; o <<= 1) { float u = __shfl_up(v, o); if (lane >= o) v += u; }
    float ang = off + v;
    float sn, cs;
    sincosf(ang, &sn, &cs);
    angs[lane * 33 + d] = sn;
    angc[lane * 33 + d] = cs;
  }
  __syncthreads();
  const int tt = threadIdx.x >> 2, q = threadIdx.x & 3;
  const size_t base = (t0 + tt) * 8192 + 4096 + h * 64 + q * 16;
  #pragma unroll
  for (int m = 0; m < 2; ++m) {   // m=0: B, m=1: C
    bf16* p = proj + base + m * 2048;
    bf16x8 v0 = *(const bf16x8*)(p);
    bf16x8 v1 = *(const bf16x8*)(p + 8);
    bf16x8 r0, r1;
    #pragma unroll
    for (int pp = 0; pp < 4; ++pp) {
      int d = q * 8 + pp;
      float e1 = (float)v0[2 * pp], e2 = (float)v0[2 * pp + 1];
      float sn = angs[tt * 33 + d], cs = angc[tt * 33 + d];
      r0[2 * pp]     = (bf16)(cs * e1 - sn * e2);
      r0[2 * pp + 1] = (bf16)(sn * e1 + cs * e2);
    }
    #pragma unroll
    for (int pp = 0; pp < 4; ++pp) {
      int d = q * 8 + 4 + pp;
      float e1 = (float)v1[2 * pp], e2 = (float)v1[2 * pp + 1];
      float sn = angs[tt * 33 + d], cs = angc[tt * 33 + d];
      r1[2 * pp]     = (bf16)(cs * e1 - sn * e2);
      r1[2 * pp + 1] = (bf16)(sn * e1 + cs * e2);
    }
    *(bf16x8*)(p) = r0;
    *(bf16x8*)(p + 8) = r1;
  }
}

// ---------------------------------------------------------------------------
// SSD stage 1 (MFMA), one block per (b,c,h) with blk = b*2048+c*32+h.
__global__ __launch_bounds__(256) void ssd1_kernel(
    const bf16* __restrict__ proj, const float* __restrict__ a_buf,
    bf16* __restrict__ Bx, bf16* __restrict__ states,
    float* __restrict__ rowsum, float* __restrict__ expac, float* __restrict__ dchunk)
{
  __shared__ bf16 Xs[64 * 72], Bs[64 * 72];
  __shared__ float acum[64], dsv[64];
  const int blk = blockIdx.x;
  const int h = blk & 31;
  const size_t bs0 = ((size_t)(blk >> 5)) * 64;
  const int tid = threadIdx.x;
  const int l = tid >> 2, p0 = (tid & 3) * 16;
  {
    const bf16* xrow = proj + (bs0 + l) * 8192 + 2048 + h * 64 + p0;
    *(bf16x8*)&Xs[l * 72 + p0]     = ((const bf16x8*)xrow)[0];
    *(bf16x8*)&Xs[l * 72 + p0 + 8] = ((const bf16x8*)xrow)[1];
    const bf16* brow = proj + (bs0 + l) * 8192 + 4096 + h * 64 + p0;
    *(bf16x8*)&Bs[l * 72 + p0]     = ((const bf16x8*)brow)[0];
    *(bf16x8*)&Bs[l * 72 + p0 + 8] = ((const bf16x8*)brow)[1];
  }
  if (tid < 64) {
    float v = a_buf[(bs0 + tid) * 32 + h];
    #pragma unroll
    for (int o = 1; o < 64; o <<= 1) { float u = __shfl_up(v, o); if (tid >= o) v += u; }
    acum[tid] = v;
    float a63 = __shfl(v, 63);
    dsv[tid] = expf(a63 - v);
    expac[(size_t)blk * 64 + tid] = expf(v);
    if (tid == 63) dchunk[blk] = expf(v);
  }
  __syncthreads();
  {
    float al = acum[l];
    float rs = 0.f;
    for (int s = tid & 3; s <= l; s += 4) rs += expf(al - acum[s]);
    rs += __shfl_xor(rs, 1);
    rs += __shfl_xor(rs, 2);
    if ((tid & 3) == 0) rowsum[(size_t)blk * 64 + l] = rs + (float)(63 - l);
  }
  const int wv = tid >> 6, lane = tid & 63;
  const int mi = lane & 15, kq = lane >> 4;
  const int m0 = wv * 16;
  fx4 accB[4], accS[4];
  #pragma unroll
  for (int j4 = 0; j4 < 4; ++j4) { fx4 z = {0.f,0.f,0.f,0.f}; accB[j4] = z; accS[j4] = z; }
  #pragma unroll
  for (int kk = 0; kk < 2; ++kk) {
    const int lb = kk * 32 + kq * 8;
    bf16x8 aX, aXd;
    #pragma unroll
    for (int j = 0; j < 8; ++j) {
      bf16 xv = Xs[(lb + j) * 72 + m0 + mi];
      aX[j] = xv;
      aXd[j] = (bf16)((float)xv * dsv[lb + j]);
    }
    #pragma unroll
    for (int j4 = 0; j4 < 4; ++j4) {
      bf16x8 bB;
      #pragma unroll
      for (int j = 0; j < 8; ++j) bB[j] = Bs[(lb + j) * 72 + j4 * 16 + mi];
      accB[j4] = __builtin_amdgcn_mfma_f32_16x16x32_bf16(aX, bB, accB[j4], 0, 0, 0);
      accS[j4] = __builtin_amdgcn_mfma_f32_16x16x32_bf16(aXd, bB, accS[j4], 0, 0, 0);
    }
  }
  const size_t obase = (size_t)blk * 4096;
  #pragma unroll
  for (int j4 = 0; j4 < 4; ++j4) {
    #pragma unroll
    for (int r = 0; r < 4; ++r) {
      int p = m0 + kq * 4 + r;
      int n = j4 * 16 + mi;
      Bx[obase + p * 64 + n] = (bf16)accB[j4][r];
      states[obase + p * 64 + n] = (bf16)accS[j4][r];
    }
  }
}

// ---------------------------------------------------------------------------
// SSD stage 2: inclusive scan over chunks (f32 carry, bf16 storage).
__global__ __launch_bounds__(128) void ssd2_kernel(
    bf16* __restrict__ states, const float* __restrict__ dchunk)
{
  const int blk = blockIdx.x;  // 1024 = b(2) x h(32) x q(16)
  const int b = blk >> 9, rest = blk & 511;
  const int h = rest >> 4, q = rest & 15;
  const int e0 = q * 256 + threadIdx.x * 2;
  float fs0 = 0.f, fs1 = 0.f;
  #pragma unroll 2
  for (int c = 0; c < 64; ++c) {
    size_t idx = ((size_t)(b * 2048 + c * 32 + h) * 4096) + e0;
    float dec = dchunk[b * 2048 + c * 32 + h];
    bf16x2 st = *(const bf16x2*)(states + idx);
    fs0 = fs0 * dec + (float)st[0];
    fs1 = fs1 * dec + (float)st[1];
    bf16x2 o = { (bf16)fs0, (bf16)fs1 };
    *(bf16x2*)(states + idx) = o;
  }
}

// ---------------------------------------------------------------------------
// SSD stage 3 (MFMA), one block per (b,c,h).
__global__ __launch_bounds__(256) void ssd3_kernel(
    bf16* proj, const bf16* __restrict__ Bx, const bf16* __restrict__ FS,
    const float* __restrict__ rowsum, const float* __restrict__ expac,
    const float* __restrict__ xsum, const float* __restrict__ D_param)
{
  __shared__ bf16 Cs[64 * 72], BxS[64 * 72], FSs[64 * 72];
  __shared__ float rs_s[64], ea_s[64], sk_s[64];
  const int blk = blockIdx.x;
  const int h = blk & 31;
  const size_t bs0 = ((size_t)(blk >> 5)) * 64;
  const int tid = threadIdx.x;
  const int l = tid >> 2, q0 = (tid & 3) * 16;
  {
    const bf16* crow = proj + (bs0 + l) * 8192 + 6144 + h * 64 + q0;
    *(bf16x8*)&Cs[l * 72 + q0]     = ((const bf16x8*)crow)[0];
    *(bf16x8*)&Cs[l * 72 + q0 + 8] = ((const bf16x8*)crow)[1];
    size_t mb = (size_t)blk * 4096 + l * 64 + q0;
    *(bf16x8*)&BxS[l * 72 + q0]     = ((const bf16x8*)(Bx + mb))[0];
    *(bf16x8*)&BxS[l * 72 + q0 + 8] = ((const bf16x8*)(Bx + mb))[1];
    *(bf16x8*)&FSs[l * 72 + q0]     = ((const bf16x8*)(FS + mb))[0];
    *(bf16x8*)&FSs[l * 72 + q0 + 8] = ((const bf16x8*)(FS + mb))[1];
  }
  if (tid < 64) {
    rs_s[tid] = rowsum[(size_t)blk * 64 + tid];
    ea_s[tid] = expac[(size_t)blk * 64 + tid];
    sk_s[tid] = D_param[h] * xsum[(bs0 + tid) * 32 + h];
  }
  __syncthreads();
  const int wv = tid >> 6, lane = tid & 63;
  const int mi = lane & 15, kq = lane >> 4;
  const int m0 = wv * 16;
  fx4 acc1[4], acc2[4];
  #pragma unroll
  for (int j4 = 0; j4 < 4; ++j4) { fx4 z = {0.f,0.f,0.f,0.f}; acc1[j4] = z; acc2[j4] = z; }
  #pragma unroll
  for (int kk = 0; kk < 2; ++kk) {
    bf16x8 aC = *(const bf16x8*)&Cs[(m0 + mi) * 72 + kk * 32 + kq * 8];
    #pragma unroll
    for (int j4 = 0; j4 < 4; ++j4) {
      bf16x8 bx = *(const bf16x8*)&BxS[(j4 * 16 + mi) * 72 + kk * 32 + kq * 8];
      bf16x8 fs = *(const bf16x8*)&FSs[(j4 * 16 + mi) * 72 + kk * 32 + kq * 8];
      acc1[j4] = __builtin_amdgcn_mfma_f32_16x16x32_bf16(aC, bx, acc1[j4], 0, 0, 0);
      acc2[j4] = __builtin_amdgcn_mfma_f32_16x16x32_bf16(aC, fs, acc2[j4], 0, 0, 0);
    }
  }
  #pragma unroll
  for (int j4 = 0; j4 < 4; ++j4) {
    #pragma unroll
    for (int r = 0; r < 4; ++r) {
      int li = m0 + kq * 4 + r;
      int p = j4 * 16 + mi;
      float y = rs_s[li] * acc1[j4][r] + ea_s[li] * acc2[j4][r] + sk_s[li];
      size_t zoff = (bs0 + li) * 8192 + h * 64 + p;
      float z = (float)proj[zoff];
      proj[zoff + 2048] = (bf16)(y * z * sigmoid_f(z));
    }
  }
}

// ---------------------------------------------------------------------------
__global__ __launch_bounds__(256) void silu_mul_kernel(
    const bf16* __restrict__ gu, bf16* __restrict__ m)
{
  const size_t row = blockIdx.y;
  const int col2 = blockIdx.x * 256 + threadIdx.x;  // 0..1279
  const size_t gi = row * 5120 + col2 * 2;
  bf16x2 g = *(const bf16x2*)(gu + gi);
  bf16x2 u = *(const bf16x2*)(gu + gi + 2560);
  float g0 = (float)g[0], g1 = (float)g[1];
  float m0 = g0 * sigmoid_f(g0) * (float)u[0];
  float m1 = g1 * sigmoid_f(g1) * (float)u[1];
  bf16x2 mv = { (bf16)m0, (bf16)m1 };
  *(bf16x2*)(m + row * 2560 + col2 * 2) = mv;
}

// ---------------------------------------------------------------------------
extern "C" void kernel_launch(void* const* d_in, const int* in_sizes, int n_in,
                              void* d_out, int out_size, void* d_ws, size_t ws_size,
                              hipStream_t stream) {
  (void)in_sizes; (void)n_in; (void)out_size;
  if (ws_size < WS_NEEDED) return;  // diagnostic guard: fail absmax, not SIGABRT
  const float* x       = (const float*)d_in[0];
  const float* n1w     = (const float*)d_in[1];
  const float* n2w     = (const float*)d_in[2];
  const float* W_in    = (const float*)d_in[3];
  const float* W_out   = (const float*)d_in[4];
  const float* A_log   = (const float*)d_in[5];
  const float* D_param = (const float*)d_in[6];
  const float* dt_bias = (const float*)d_in[7];
  const float* B_bias  = (const float*)d_in[8];
  const float* C_bias  = (const float*)d_in[9];
  const float* Bn_w    = (const float*)d_in[10];
  const float* Cn_w    = (const float*)d_in[11];
  const float* Wg      = (const float*)d_in[12];
  const float* Wu      = (const float*)d_in[13];
  const float* Wd      = (const float*)d_in[14];
  float* out = (float*)d_out;
  char* ws = (char*)d_ws;

  bf16*  proj   = (bf16*)(ws + OFF_PROJ);
  float* projT  = (float*)(ws + OFF_PROJT);
  bf16*  h_hi   = (bf16*)(ws + OFF_HHI);
  bf16*  h_lo   = (bf16*)(ws + OFF_HLO);
  bf16*  Wt_in  = (bf16*)(ws + OFF_WTIN);
  bf16*  Wt_hi  = (bf16*)(ws + OFF_WTHI);
  bf16*  Wt_lo  = (bf16*)(ws + OFF_WTLO);
  bf16*  Wt_out = (bf16*)(ws + OFF_WTOUT);
  bf16*  Wt_gu  = (bf16*)(ws + OFF_WTGU);
  bf16*  Wt_d   = (bf16*)(ws + OFF_WTD);
  bf16*  Bx     = (bf16*)(ws + OFF_BX);
  bf16*  states = (bf16*)(ws + OFF_STATES);
  float* a_buf  = (float*)(ws + OFF_ABUF);
  float* xsum_  = (float*)(ws + OFF_XSUM);
  float* rowsum = (float*)(ws + OFF_ROWSUM);
  float* expac  = (float*)(ws + OFF_EXPA);
  float* dchunk = (float*)(ws + OFF_DCHUNK);
  float* gamma_ = (float*)(ws + OFF_GAMMA);
  float* Ssum   = (float*)(ws + OFF_HLO);    // 512KB chunk sums (h_lo dead by then)
  bf16*  ybf    = proj + 2048;               // cols [2048,4096) of proj, lda 8192
  bf16*  gubf   = (bf16*)(ws + OFF_GU);
  bf16*  mbf    = (bf16*)(ws + OFF_MBF);
  bf16*  h2bf   = h_hi;                      // reuse after proj GEMMs
  float* x2     = out;                       // x2 lives in d_out

  // --- weight transposes needed up-front ---
  transpose_cast<<<dim3(256, 32), 256, 0, stream>>>(W_in, 9248, 0, Wt_in, 1024, 8192);
  transpose_cast_hilo<<<dim3(36, 32), 256, 0, stream>>>(W_in, 9248, 8192, Wt_hi, Wt_lo, 1024, 1056);

  // --- norm1 (hi/lo split for the precision-critical dt/theta tail GEMM) ---
  rmsnorm_kernel<<<8192, 256, 0, stream>>>(x, n1w, h_hi, h_lo);

  // --- in-projection: fused hi/lo tail, then dt, then proj w/ fused prep ---
  gemm_tail<<<dim3(9, 64), 256, 0, stream>>>(h_hi, h_lo, Wt_hi, Wt_lo, projT);
  dt_kernel<<<1024, 256, 0, stream>>>(projT, A_log, dt_bias, a_buf, gamma_);
  gemm_proj<<<dim3(64, 64), 256, 0, stream>>>(h_hi, Wt_in, proj, gamma_, xsum_,
                                              Bn_w, Cn_w, B_bias, C_bias);

  // --- hierarchical RoPE ---
  chunk_sum_kernel<<<dim3(128, 4), 256, 0, stream>>>(projT, Ssum);
  rope_kernel<<<4096, 256, 0, stream>>>(proj, projT, Ssum);

  // --- SSD (MFMA) ---
  ssd1_kernel<<<4096, 256, 0, stream>>>(proj, a_buf, Bx, states, rowsum, expac, dchunk);
  ssd2_kernel<<<1024, 128, 0, stream>>>(states, dchunk);
  ssd3_kernel<<<4096, 256, 0, stream>>>(proj, Bx, states, rowsum, expac, xsum_, D_param);

  // --- late weight transposes (overlay dead states region) ---
  transpose_cast<<<dim3(32, 64), 256, 0, stream>>>(W_out, 1024, 0, Wt_out, 2048, 1024);
  transpose_cast<<<dim3(80, 32), 256, 0, stream>>>(Wg, 2560, 0, Wt_gu, 1024, 2560);
  transpose_cast<<<dim3(80, 32), 256, 0, stream>>>(Wu, 2560, 0, Wt_gu + (size_t)2560 * 1024, 1024, 2560);
  transpose_cast<<<dim3(32, 80), 256, 0, stream>>>(Wd, 1024, 0, Wt_d, 2560, 1024);

  // --- out-projection + residual (x2 -> d_out) ---
  gemm_bt<2><<<dim3(8, 64), 256, 0, stream>>>(ybf, Wt_out, x2, x, 2048, 8192, 1024);

  // --- MLP ---
  rmsnorm_kernel<<<8192, 256, 0, stream>>>(x2, n2w, h2bf, nullptr);
  gemm_bt<1><<<dim3(40, 64), 256, 0, stream>>>(h2bf, Wt_gu, gubf, nullptr, 1024, 1024, 5120);
  silu_mul_kernel<<<dim3(5, 8192), 256, 0, stream>>>(gubf, mbf);
  gemm_bt<2><<<dim3(8, 64), 256, 0, stream>>>(mbf, Wt_d, out, x2, 2560, 2560, 1024);
}